// Round 10
// baseline (2623.625 us; speedup 1.0000x reference)
//
#include <hip/hip_runtime.h>
#include <cmath>

// ---------------------------------------------------------------------------
// S2CNN regressor forward, full pipeline in fp32.
// Fast path (ws >= ~113MB): per transition
//   k_mix (mix + Gram-based BN stats, Z cached to ws) -> k_bnred ->
//   k_finv (k-register-blocked inverse + BN + ReLU + forward + accumulate,
//           AL=2 tiling in the iDFT-m phase, float4 transposed W tables).
// Round 10: T0 k-block KB 4 -> 8 (halves per-operand LDS traffic + barriers).
// Fallback path (small ws): round-2 recompute design (~47MB).
// ---------------------------------------------------------------------------

#define NSAMP 1472   // 64 batch * 23 atoms
#define PI_D 3.14159265358979323846

constexpr int cBI[4] = {10, 8, 6, 4};
constexpr int cBO[4] = {8, 6, 4, 2};
constexpr int cFI[4] = {5, 8, 16, 32};
constexpr int cFO[4] = {8, 16, 32, 64};
constexpr int cG [4] = {40, 64, 48, 32};
constexpr int cSQ[4] = {680, 286, 84, 10};   // sum_{l<b_out} (2l+1)^2

__host__ __device__ constexpr int zof(int l) { return (4*l*l*l - l)/3; }
constexpr int cmax2(int a, int b){ return a > b ? a : b; }
constexpr int cmax3(int a, int b, int c){ return cmax2(cmax2(a,b), c); }

// ---------------- workspace layout (float units) ----------------
constexpr size_t al64(size_t x){ return (x + 63) & ~(size_t)63; }
constexpr size_t OFS_WF0 = 0;
constexpr size_t OFS_WF1 = al64(OFS_WF0 + 20*64);
constexpr size_t OFS_WF2 = al64(OFS_WF1 + 16*286);
constexpr size_t OFS_WF3 = al64(OFS_WF2 + 12*84);
constexpr size_t OFS_WI0 = al64(OFS_WF3 + 8*10);
constexpr size_t OFS_WI1 = al64(OFS_WI0 + 16*680);
constexpr size_t OFS_WI2 = al64(OFS_WI1 + 12*286);
constexpr size_t OFS_WI3 = al64(OFS_WI2 + 8*84);
constexpr size_t OFS_BC0 = al64(OFS_WI3 + 4*10);
constexpr size_t OFS_BC1 = al64(OFS_BC0 + 2*40*64);
constexpr size_t OFS_BC2 = al64(OFS_BC1 + 2*64*286);
constexpr size_t OFS_BC3 = al64(OFS_BC2 + 2*48*84);
constexpr size_t OFS_FF0 = al64(OFS_BC3 + 2*32*10);
constexpr size_t OFS_FF1 = al64(OFS_FF0 + 2*20*15);
constexpr size_t OFS_FF2 = al64(OFS_FF1 + 2*16*11);
constexpr size_t OFS_FF3 = al64(OFS_FF2 + 2*12*7);
constexpr size_t OFS_FI0 = al64(OFS_FF3 + 2*8*3);
constexpr size_t OFS_FI1 = al64(OFS_FI0 + 2*16*15);
constexpr size_t OFS_FI2 = al64(OFS_FI1 + 2*12*11);
constexpr size_t OFS_FI3 = al64(OFS_FI2 + 2*8*7);
constexpr size_t OFS_QWI = al64(OFS_FI3 + 2*4*3);
constexpr size_t OFS_YC0 = al64(OFS_QWI + 4);
constexpr size_t OFS_YC1 = al64(OFS_YC0 + 2*5*8*64);
constexpr size_t OFS_YC2 = al64(OFS_YC1 + 2*8*16*286);
constexpr size_t OFS_YC3 = al64(OFS_YC2 + 2*16*32*84);
constexpr size_t OFS_BNP = al64(OFS_YC3 + 2*32*64*10);
constexpr size_t OFS_BNS = al64(OFS_BNP + (size_t)2*64*NSAMP);
constexpr size_t OFS_ST1 = al64(OFS_BNS + 512);
constexpr size_t OFS_ST2 = al64(OFS_ST1 + 512);
constexpr size_t OFS_ST3 = al64(OFS_ST2 + 128);
constexpr size_t OFS_GOUT= al64(OFS_ST3 + 1024);
constexpr size_t OFS_PRE1= al64(OFS_GOUT + (size_t)NSAMP*64);
constexpr size_t OFS_PRE2= al64(OFS_PRE1 + (size_t)NSAMP*256);
constexpr size_t OFS_SM  = al64(OFS_PRE2 + (size_t)NSAMP*64);
constexpr size_t OFS_PRE3= al64(OFS_SM + 64*64);
constexpr size_t OFS_XA  = al64(OFS_PRE3 + 64*512);
constexpr size_t OFS_XB  = al64(OFS_XA + (size_t)2*NSAMP*16*84);
constexpr size_t WS_FLOATS = OFS_XB + (size_t)2*NSAMP*8*286;
constexpr size_t OFS_G0 = al64(WS_FLOATS);
constexpr size_t OFS_G1 = al64(OFS_G0 + 64*225);
constexpr size_t OFS_G2 = al64(OFS_G1 + 36*121);
constexpr size_t OFS_H0 = al64(OFS_G2 + 16*49);
constexpr size_t OFS_H1 = OFS_H0 + 8;
constexpr size_t OFS_H2 = OFS_H1 + 8;
constexpr size_t OFS_Z  = al64(OFS_H2 + 8);
constexpr size_t OFS_WIT0 = al64(OFS_Z + (size_t)2*NSAMP*8*680);
constexpr size_t OFS_WIT1 = al64(OFS_WIT0 + 680*16);
constexpr size_t OFS_WIT2 = al64(OFS_WIT1 + 286*12);
constexpr size_t OFS_WFT1 = al64(OFS_WIT2 + 84*8);
constexpr size_t OFS_WFT2 = al64(OFS_WFT1 + 286*16);
constexpr size_t OFS_WFT3 = al64(OFS_WFT2 + 84*12);
constexpr size_t WS_BIG = al64(OFS_WFT3 + 10*8);   // ~113MB

// ---------------- device math helpers (double, init only) ----------------
__device__ double dfact(int n){ double r = 1.0; for (int i = 2; i <= n; ++i) r *= (double)i; return r; }
__device__ double dipow(double x, int n){ double r = 1.0; for (int i = 0; i < n; ++i) r *= x; return r; }

__device__ double dwig(int l, int mp, int m, double beta){
    double cb = cos(0.5*beta), sb = sin(0.5*beta);
    double pref = sqrt(dfact(l+mp)*dfact(l-mp)*dfact(l+m)*dfact(l-m));
    int s0 = (m - mp > 0) ? (m - mp) : 0;
    int s1 = (l + m < l - mp) ? (l + m) : (l - mp);
    double acc = 0.0;
    for (int s = s0; s <= s1; ++s){
        double t = 1.0/(dfact(l+m-s)*dfact(s)*dfact(mp-m+s)*dfact(l-mp-s));
        t *= dipow(cb, 2*l + m - mp - 2*s) * dipow(sb, mp - m + 2*s);
        acc += ((mp - m + s) & 1) ? -t : t;
    }
    return pref*acc;
}

__device__ double dqw(int b, int j){
    double s = 0.0;
    for (int k = 0; k < b; ++k) s += sin((2*j+1)*(2*k+1)*PI_D/(4.0*b)) / (2*k+1);
    return 2.0/b * sin(PI_D*(2*j+1)/(4.0*b)) * s;
}

// ---------------- init kernels ----------------
__global__ void k_init_wf(float* dst, int b_in, int nl, int s2mode){
    int P = 2*b_in;
    int total = 0;
    for (int l = 0; l < nl; ++l){ int w = 2*l+1; total += P * (s2mode ? w : w*w); }
    for (int idx = blockIdx.x*blockDim.x + threadIdx.x; idx < total; idx += gridDim.x*blockDim.x){
        int rem = idx, l = 0;
        for (;;){ int w = 2*l+1; int blk = P*(s2mode ? w : w*w); if (rem < blk) break; rem -= blk; ++l; }
        int w = 2*l+1, szl = s2mode ? w : w*w;
        int k = rem / szl, rc = rem % szl;
        double beta = PI_D*(2*k+1)/(4.0*b_in);
        double val = s2mode ? dwig(l, rc - l, 0, beta)
                            : dwig(l, rc / w - l, rc % w - l, beta);
        dst[idx] = (float)(val * dqw(b_in, k));
    }
}

__global__ void k_init_wi(float* dst, int b_out, int nl){
    int P = 2*b_out;
    int total = 0;
    for (int l = 0; l < nl; ++l){ int w = 2*l+1; total += P*w*w; }
    for (int idx = blockIdx.x*blockDim.x + threadIdx.x; idx < total; idx += gridDim.x*blockDim.x){
        int rem = idx, l = 0;
        for (;;){ int w = 2*l+1; int blk = P*w*w; if (rem < blk) break; rem -= blk; ++l; }
        int w = 2*l+1;
        int k = rem / (w*w), rc = rem % (w*w);
        double beta = PI_D*(2*k+1)/(4.0*b_out);
        dst[idx] = (float)((2*l+1) * dwig(l, rc / w - l, rc % w - l, beta));
    }
}

// transpose [l][k][rc] -> [(zof(l)+rc)*P + k]
__global__ void k_transpose_w(const float* __restrict__ src, float* __restrict__ dst, int nl, int P){
    int total = 0;
    for (int l = 0; l < nl; ++l){ int w = 2*l+1; total += P*w*w; }
    for (int idx = blockIdx.x*blockDim.x + threadIdx.x; idx < total; idx += gridDim.x*blockDim.x){
        int rem = idx, l = 0;
        for (;;){ int w = 2*l+1; int blk = P*w*w; if (rem < blk) break; rem -= blk; ++l; }
        int w = 2*l+1, szl = w*w;
        int k = rem / szl, rc = rem % szl;
        dst[(zof(l) + rc)*P + k] = src[P*zof(l) + k*szl + rc];
    }
}

__global__ void k_init_gram(const float* __restrict__ Wi, float* __restrict__ G,
                            float* __restrict__ h, int NL){
    int P = 2*NL, NF = 2*NL-1, OFF = NL-1;
    int total = NL*NL*NF*NF;
    for (int idx = blockIdx.x*blockDim.x + threadIdx.x; idx < total; idx += gridDim.x*blockDim.x){
        int ni = idx % NF, mi = (idx/NF) % NF;
        int l2 = (idx/(NF*NF)) % NL, l = idx/(NF*NF*NL);
        int mm = mi - OFF, nn = ni - OFF;
        int am = mm<0?-mm:mm, an = nn<0?-nn:nn;
        int l0 = am > an ? am : an;
        float acc = 0.f;
        if (l >= l0 && l2 >= l0){
            int w = 2*l+1, w2 = 2*l2+1;
            const float* p1 = Wi + P*zof(l)  + (mm+l )*w  + (nn+l );
            const float* p2 = Wi + P*zof(l2) + (mm+l2)*w2 + (nn+l2);
            for (int k = 0; k < P; ++k) acc += p1[k*w*w]*p2[k*w2*w2];
        }
        G[idx] = acc;
    }
    int gi = blockIdx.x*blockDim.x + threadIdx.x;
    if (gi < NL){
        int w = 2*gi+1;
        const float* p = Wi + P*zof(gi) + gi*w + gi;
        float acc = 0.f;
        for (int k = 0; k < P; ++k) acc += p[k*w*w];
        h[gi] = acc;
    }
}

__global__ void k_init_basis_so3(float2* dst, int n_alpha, int nl, int G, float scale){
    int total = 0;
    for (int l = 0; l < nl; ++l){ int w = 2*l+1; total += G*w*w; }
    for (int idx = blockIdx.x*blockDim.x + threadIdx.x; idx < total; idx += gridDim.x*blockDim.x){
        int rem = idx, l = 0;
        for (;;){ int w = 2*l+1; int blk = G*w*w; if (rem < blk) break; rem -= blk; ++l; }
        int w = 2*l+1;
        int g = rem / (w*w), rc = rem % (w*w);
        int mu = rc / w - l, nu = rc % w - l;
        int bi = g / (n_alpha*2), rr = g % (n_alpha*2);
        int ai = rr / 2, gi = rr % 2;
        double beta  = (bi + 1) * PI_D / 16.0;
        double alpha = 2.0*PI_D*ai / n_alpha;
        double gamma = gi ? PI_D/8.0 : -PI_D/8.0;
        double d = dwig(l, mu, nu, beta);
        double ph = mu*alpha + nu*gamma;
        dst[idx] = make_float2((float)(scale*d*cos(ph)), (float)(scale*d*sin(ph)));
    }
}

__global__ void k_init_basis_s2(float2* dst, float scale){
    int total = 40*64;
    for (int idx = blockIdx.x*blockDim.x + threadIdx.x; idx < total; idx += gridDim.x*blockDim.x){
        int rem = idx, l = 0;
        for (;;){ int w = 2*l+1; int blk = 40*w; if (rem < blk) break; rem -= blk; ++l; }
        int w = 2*l+1;
        int g = rem / w, mu = rem % w - l;
        int bi = g / 20, ai = g % 20;
        double beta  = (bi + 1) * PI_D / 16.0;
        double alpha = 2.0*PI_D*ai / 20.0;
        double d = dwig(l, mu, 0, beta);
        double ph = mu*alpha;
        dst[idx] = make_float2((float)(scale*d*cos(ph)), (float)(scale*d*sin(ph)));
    }
}

__global__ void k_init_dft(float2* dst, int P, int NF, double sign){
    int off = (NF - 1) / 2;
    int total = P*NF;
    for (int idx = blockIdx.x*blockDim.x + threadIdx.x; idx < total; idx += gridDim.x*blockDim.x){
        int j = idx / NF, mi = idx % NF;
        double arg = sign * 2.0 * PI_D * (double)j * (double)(mi - off) / (double)P;
        dst[idx] = make_float2((float)cos(arg), (float)sin(arg));
    }
}

__global__ void k_init_qwi(float* dst){
    int k = threadIdx.x;
    if (k < 4) dst[k] = (float)(dqw(2, k) / 16.0);
}

// ---------------- Y = kern (x) basis ----------------
template<int T>
__global__ __launch_bounds__(256)
void k_mkY_so3(const float2* __restrict__ Bc, const float* __restrict__ kern, float2* __restrict__ YC){
    constexpr int FI = cFI[T], FO = cFO[T], G = cG[T];
    int l = blockIdx.y;
    int w = 2*l+1, szl = w*w;
    int bbase = 0, ybase = 0;
    for (int l2 = 0; l2 < l; ++l2){ int w2 = 2*l2+1; bbase += G*w2*w2; ybase += FI*FO*w2*w2; }
    int tot = FI*FO*szl;
    for (int t = blockIdx.x*256 + threadIdx.x; t < tot; t += gridDim.x*256){
        int n = t % w, o = (t/w) % FO, k = (t/(w*FO)) % w, i = t/(w*FO*w);
        float re = 0.f, im = 0.f;
        const float* kr = kern + ((size_t)i*FO + o)*G;
        for (int g = 0; g < G; ++g){
            float kv = kr[g];
            float2 b = Bc[bbase + (g*w + n)*w + k];
            re += kv*b.x; im += kv*b.y;
        }
        YC[ybase + t] = make_float2(re, im);
    }
}

__global__ __launch_bounds__(256)
void k_mkY_s2(const float2* __restrict__ Bc, const float* __restrict__ kern, float2* __restrict__ YC){
    int l = blockIdx.y;
    int w = 2*l+1;
    int bbase = 40*l*l, ybase = 40*l*l;
    int tot = 5*8*w;
    for (int t = blockIdx.x*256 + threadIdx.x; t < tot; t += gridDim.x*256){
        int n = t % w, o = (t/w) % 8, i = t/(w*8);
        float re = 0.f, im = 0.f;
        const float* kr = kern + ((size_t)i*8 + o)*40;
        for (int g = 0; g < 40; ++g){
            float kv = kr[g];
            float2 b = Bc[bbase + g*w + n];
            re += kv*b.x; im += kv*b.y;
        }
        YC[ybase + t] = make_float2(re, im);
    }
}

// ---------------- s2 forward ----------------
__global__ __launch_bounds__(256)
void k_fwd_s2(const float* __restrict__ x, float2* __restrict__ X,
              const float2* __restrict__ Ff, const float* __restrict__ Wf){
    __shared__ float xv[400];
    __shared__ float2 xf[300];
    int tid = threadIdx.x;
    const float* src = x + (size_t)blockIdx.x * 400;
    for (int t = tid; t < 400; t += 256) xv[t] = src[t];
    __syncthreads();
    for (int t = tid; t < 300; t += 256){
        int mi = t % 15, b = t / 15;
        float re = 0.f, im = 0.f;
        for (int al = 0; al < 20; ++al){
            float v = xv[b*20 + al];
            float2 e = Ff[al*15 + mi];
            re += v*e.x; im += v*e.y;
        }
        xf[t] = make_float2(re, im);
    }
    __syncthreads();
    float2* dst = X + (size_t)blockIdx.x * 64;
    int base = 0, lo = 0;
    for (int l = 0; l < 8; ++l){
        int w = 2*l+1;
        for (int t = tid; t < w; t += 256){
            int mi = t - l + 7;
            float re = 0.f, im = 0.f;
            for (int b = 0; b < 20; ++b){
                float wv = Wf[base + b*w + t];
                float2 v = xf[b*15 + mi];
                re += wv*v.x; im += wv*v.y;
            }
            dst[lo + t] = make_float2(re, im);
        }
        base += 20*w; lo += w;
    }
}

// ---------------- fast path: mix kernel (Z + Gram stats) ----------------
template<int T, int L>
__device__ inline float2 mixE(const float2* __restrict__ xs, const float2* __restrict__ Y,
                              int o, int m, int n){
    constexpr int w = 2*L+1;
    constexpr int FI = cFI[T], FO = cFO[T], SQ = cSQ[T];
    float re = 0.f, im = 0.f;
    if constexpr (T == 0){
        const float2* yb = Y + 40*L*L + o*w + n;
        #pragma unroll
        for (int i = 0; i < FI; ++i){
            float2 x = xs[i*64 + L*L + m];
            float2 y = yb[i*8*w];
            re += x.x*y.x - x.y*y.y;
            im += x.x*y.y + x.y*y.x;
        }
    } else {
        const float2* yb = Y + FI*FO*zof(L) + (size_t)o*w + n;
        for (int i = 0; i < FI; ++i){
            const float2* xp = xs + i*SQ + zof(L) + m*w;
            const float2* yp = yb + (size_t)i*w*FO*w;
            #pragma unroll
            for (int k = 0; k < w; ++k){
                float2 x = xp[k];
                float2 y = yp[(size_t)k*FO*w];
                re += x.x*y.x - x.y*y.y;
                im += x.x*y.y + x.y*y.x;
            }
        }
    }
    return make_float2(re, im);
}

template<int T, int OB>
__global__ __launch_bounds__(256)
void k_mix(const float2* __restrict__ Xin, const float2* __restrict__ Y,
           const float* __restrict__ G, const float* __restrict__ hT,
           float2* __restrict__ Z, float2* __restrict__ bnp)
{
    constexpr int FI = cFI[T], FO = cFO[T], NL = cBO[T];
    constexpr int NF = 2*NL-1, OFF = NL-1, SQ = cSQ[T], P = 2*NL;
    constexpr int XPER = (T==0) ? 64 : SQ;
    __shared__ float2 xs[FI*XPER];
    __shared__ float2 zs[OB*SQ];
    const int tid = threadIdx.x;
    constexpr int NOB = FO/OB;
    const int o0 = (blockIdx.x % NOB)*OB;
    const int a  = blockIdx.x / NOB;
    for (int t = tid; t < FI*XPER; t += 256) xs[t] = Xin[(size_t)a*FI*XPER + t];
    __syncthreads();
    float2* Zg = Z + ((size_t)a*FO + o0)*SQ;
    for (int e = tid; e < OB*SQ; e += 256){
        int osub = e / SQ, rem = e % SQ;
        int o = o0 + osub;
        int l = 0, r2 = rem;
        while (r2 >= (2*l+1)*(2*l+1)){ r2 -= (2*l+1)*(2*l+1); ++l; }
        int w = 2*l+1;
        int m = r2 / w, n = r2 % w;
        float2 val = make_float2(0.f, 0.f);
        switch(l){
            case 0: val = mixE<T,0>(xs, Y, o, m, n); break;
            case 1: if constexpr (1 < NL) val = mixE<T,1>(xs, Y, o, m, n); break;
            case 2: if constexpr (2 < NL) val = mixE<T,2>(xs, Y, o, m, n); break;
            case 3: if constexpr (3 < NL) val = mixE<T,3>(xs, Y, o, m, n); break;
            case 4: if constexpr (4 < NL) val = mixE<T,4>(xs, Y, o, m, n); break;
            case 5: if constexpr (5 < NL) val = mixE<T,5>(xs, Y, o, m, n); break;
            case 6: if constexpr (6 < NL) val = mixE<T,6>(xs, Y, o, m, n); break;
            case 7: if constexpr (7 < NL) val = mixE<T,7>(xs, Y, o, m, n); break;
        }
        zs[e] = val;
        Zg[(size_t)osub*SQ + rem] = val;
    }
    __syncthreads();
    const int wave = tid >> 6, lane = tid & 63;
    for (int osub = wave; osub < OB; osub += 4){
        const float2* zp = zs + osub*SQ;
        float pq = 0.f, p0 = 0.f;
        for (int e = lane; e < NF*NF; e += 64){
            int mi = e / NF, ni = e % NF;
            int mm = mi - OFF, nn = ni - OFF;
            int am = mm<0?-mm:mm, an = nn<0?-nn:nn;
            float zr[8], zi[8];
            #pragma unroll
            for (int l = 0; l < NL; ++l){
                bool ok = (l >= am) && (l >= an);
                int idx = ok ? (zof(l) + (mm+l)*(2*l+1) + (nn+l)) : 0;
                float2 zv = zp[idx];
                zr[l] = ok ? zv.x : 0.f;
                zi[l] = ok ? zv.y : 0.f;
            }
            #pragma unroll
            for (int l = 0; l < NL; ++l){
                #pragma unroll
                for (int l2 = 0; l2 < NL; ++l2){
                    float g = G[(l*NL + l2)*NF*NF + e];
                    pq += g*(zr[l]*zr[l2] + zi[l]*zi[l2]);
                }
            }
        }
        if (lane < NL){
            int l = lane;
            p0 = hT[l] * zp[zof(l) + l*(2*l+1) + l].x;
        }
        for (int s = 32; s > 0; s >>= 1){ p0 += __shfl_down(p0, s); pq += __shfl_down(pq, s); }
        if (lane == 0) bnp[(size_t)(o0+osub)*NSAMP + a] = make_float2((float)(P*P)*p0, (float)(P*P)*pq);
    }
}

// ---------------- fast path: k-register-blocked inverse+BN+ReLU+forward ----------------
// WiT/WfT are k-innermost transposed tables -> float4 global loads.
// Phase B uses AL=2 tiling (al, al+P/2) to halve per-FLOP LDS bytes.
template<int T, int OB, int KB>
__global__ __launch_bounds__(256)
void k_finv(const float2* __restrict__ Z, const float* __restrict__ WiT, const float2* __restrict__ Fi,
            const float2* __restrict__ Ff, const float* __restrict__ WfT,
            const float* __restrict__ st, const float* __restrict__ gam, const float* __restrict__ bet,
            float2* __restrict__ Xout)
{
    constexpr int FO = cFO[T], NL = cBO[T];
    constexpr int P = 2*NL, NF = 2*NL-1, OFF = NL-1, SQ = cSQ[T];
    constexpr int Tn = T+1;
    constexpr int NLo = cBO[Tn], NFo = 2*NLo-1, OFFo = NLo-1, SQo = cSQ[Tn];
    constexpr float invP2 = 1.0f/(float)(P*P);
    static_assert(P % KB == 0, "KB must divide P");
    static_assert(KB % 4 == 0, "KB must be multiple of 4 for float4 tables");

    constexpr int offZS = 0;                  constexpr int szZS = OB*SQ*8;
    constexpr int offFI = offZS + szZS;       constexpr int szFI = P*NF*8;
    constexpr int offFF = offFI + szFI;       constexpr int szFF = P*NFo*8;
    constexpr int offXA = offFF + szFF;       constexpr int szXA = OB*SQo*8;
    constexpr int offR1 = offXA + szXA;
    constexpr int szR1  = cmax3(OB*KB*NF*NF*8, OB*KB*P*P*4, OB*KB*NFo*NFo*8);
    constexpr int offR2 = offR1 + szR1;       constexpr int szR2 = OB*KB*P*NF*8;
    constexpr int LDSZ  = offR2 + szR2;

    __shared__ __align__(16) char smem[LDSZ];
    float2* zs    = (float2*)(smem + offZS);
    float2* Fi_sh = (float2*)(smem + offFI);
    float2* Ff_sh = (float2*)(smem + offFF);
    float2* xacc  = (float2*)(smem + offXA);
    float2* S     = (float2*)(smem + offR1);   // region1: S / vol / spec
    float*  vol   = (float*)(smem + offR1);
    float2* spec  = (float2*)(smem + offR1);
    float2* t1    = (float2*)(smem + offR2);   // region2: t1 / t1b
    float2* t1b   = (float2*)(smem + offR2);

    const int tid = threadIdx.x;
    constexpr int NOB = FO/OB;
    const int o0 = (blockIdx.x % NOB)*OB;
    const int a  = blockIdx.x / NOB;

    for (int t = tid; t < OB*SQ; t += 256) zs[t] = Z[((size_t)a*FO + o0)*SQ + t];
    for (int t = tid; t < P*NF; t += 256)  Fi_sh[t] = Fi[t];
    for (int t = tid; t < P*NFo; t += 256) Ff_sh[t] = Ff[t];
    for (int t = tid; t < OB*SQo; t += 256) xacc[t] = make_float2(0.f, 0.f);
    __syncthreads();

    for (int k0 = 0; k0 < P; k0 += KB){
        // ---- A: S[osub][kk][mi][ni] = sum_l WiT_l[mn][k] * Z_l[mn] ----
        for (int t = tid; t < OB*NF*NF; t += 256){
            int ni = t % NF, mi = (t/NF) % NF, osub = t/(NF*NF);
            int mm = mi - OFF, nn = ni - OFF;
            int am = mm < 0 ? -mm : mm, an = nn < 0 ? -nn : nn;
            int l0 = am > an ? am : an;
            const float2* zp = zs + osub*SQ;
            float reA[KB], imA[KB];
            #pragma unroll
            for (int kk = 0; kk < KB; ++kk){ reA[kk] = 0.f; imA[kk] = 0.f; }
            int zb = zof(l0);
            for (int l = l0; l < NL; ++l){
                int w = 2*l+1, szl = w*w;
                int rc = (mm + l)*w + (nn + l);
                float2 zv = zp[zb + rc];
                const float4* wp = (const float4*)(WiT + (zb + rc)*P + k0);
                #pragma unroll
                for (int h = 0; h < KB/4; ++h){
                    float4 w4 = wp[h];
                    reA[h*4+0] += w4.x*zv.x; imA[h*4+0] += w4.x*zv.y;
                    reA[h*4+1] += w4.y*zv.x; imA[h*4+1] += w4.y*zv.y;
                    reA[h*4+2] += w4.z*zv.x; imA[h*4+2] += w4.z*zv.y;
                    reA[h*4+3] += w4.w*zv.x; imA[h*4+3] += w4.w*zv.y;
                }
                zb += szl;
            }
            #pragma unroll
            for (int kk = 0; kk < KB; ++kk)
                S[(osub*KB + kk)*NF*NF + mi*NF + ni] = make_float2(reA[kk], imA[kk]);
        }
        __syncthreads();
        // ---- B: t1[g][al][ni] = sum_mi Fi[al][mi] * S[g][mi][ni]   (AL=2 tiling) ----
        {
            constexpr int PH = P/2;
            for (int t = tid; t < OB*PH*NF; t += 256){
                int ni = t % NF, alh = (t/NF) % PH, osub = t/(NF*PH);
                int al0 = alh, al1 = alh + PH;
                float re0[KB], im0[KB], re1[KB], im1[KB];
                #pragma unroll
                for (int kk = 0; kk < KB; ++kk){ re0[kk]=0.f; im0[kk]=0.f; re1[kk]=0.f; im1[kk]=0.f; }
                for (int mi = 0; mi < NF; ++mi){
                    float2 e0 = Fi_sh[al0*NF + mi];
                    float2 e1 = Fi_sh[al1*NF + mi];
                    #pragma unroll
                    for (int kk = 0; kk < KB; ++kk){
                        float2 s = S[(osub*KB + kk)*NF*NF + mi*NF + ni];
                        re0[kk] += s.x*e0.x - s.y*e0.y;
                        im0[kk] += s.x*e0.y + s.y*e0.x;
                        re1[kk] += s.x*e1.x - s.y*e1.y;
                        im1[kk] += s.x*e1.y + s.y*e1.x;
                    }
                }
                #pragma unroll
                for (int kk = 0; kk < KB; ++kk){
                    t1[(osub*KB + kk)*P*NF + al0*NF + ni] = make_float2(re0[kk], im0[kk]);
                    t1[(osub*KB + kk)*P*NF + al1*NF + ni] = make_float2(re1[kk], im1[kk]);
                }
            }
        }
        __syncthreads();
        // ---- C: vol[g][al][ga] = relu(bn(Re sum_ni t1[g][al][ni]*Fi[ga][ni])) ----
        for (int t = tid; t < OB*P*P; t += 256){
            int ga = t % P, al = (t/P) % P, osub = t/(P*P);
            float reC[KB];
            #pragma unroll
            for (int kk = 0; kk < KB; ++kk) reC[kk] = 0.f;
            for (int ni = 0; ni < NF; ++ni){
                float2 e = Fi_sh[ga*NF + ni];
                #pragma unroll
                for (int kk = 0; kk < KB; ++kk){
                    float2 v = t1[(osub*KB + kk)*P*NF + al*NF + ni];
                    reC[kk] += v.x*e.x - v.y*e.y;
                }
            }
            int o = o0 + osub;
            float mu = st[2*o], rs = st[2*o+1], gg = gam[o], bb = bet[o];
            #pragma unroll
            for (int kk = 0; kk < KB; ++kk)
                vol[((osub*KB + kk)*P + al)*P + ga] = fmaxf(0.f, (reC[kk] - mu)*rs*gg + bb);
        }
        __syncthreads();
        // ---- E: t1b[g][j1][n] = sum_j2 vol[g][j1][j2] * Ff[j2][n] ----
        for (int t = tid; t < OB*P*NFo; t += 256){
            int n = t % NFo, j1 = (t/NFo) % P, osub = t/(NFo*P);
            float reE[KB], imE[KB];
            #pragma unroll
            for (int kk = 0; kk < KB; ++kk){ reE[kk] = 0.f; imE[kk] = 0.f; }
            for (int j2 = 0; j2 < P; ++j2){
                float2 e = Ff_sh[j2*NFo + n];
                #pragma unroll
                for (int kk = 0; kk < KB; ++kk){
                    float v = vol[((osub*KB + kk)*P + j1)*P + j2];
                    reE[kk] += v*e.x; imE[kk] += v*e.y;
                }
            }
            #pragma unroll
            for (int kk = 0; kk < KB; ++kk)
                t1b[(osub*KB + kk)*P*NFo + j1*NFo + n] = make_float2(reE[kk], imE[kk]);
        }
        __syncthreads();
        // ---- F: spec[g][m][n] = invP2 * sum_j1 Ff[j1][m] * t1b[g][j1][n] ----
        for (int t = tid; t < OB*NFo*NFo; t += 256){
            int n = t % NFo, m = (t/NFo) % NFo, osub = t/(NFo*NFo);
            float reF[KB], imF[KB];
            #pragma unroll
            for (int kk = 0; kk < KB; ++kk){ reF[kk] = 0.f; imF[kk] = 0.f; }
            for (int j1 = 0; j1 < P; ++j1){
                float2 e = Ff_sh[j1*NFo + m];
                #pragma unroll
                for (int kk = 0; kk < KB; ++kk){
                    float2 v = t1b[(osub*KB + kk)*P*NFo + j1*NFo + n];
                    reF[kk] += v.x*e.x - v.y*e.y;
                    imF[kk] += v.x*e.y + v.y*e.x;
                }
            }
            #pragma unroll
            for (int kk = 0; kk < KB; ++kk)
                spec[(osub*KB + kk)*NFo*NFo + m*NFo + n] = make_float2(reF[kk]*invP2, imF[kk]*invP2);
        }
        __syncthreads();
        // ---- G: Wigner-projected accumulate (WfT float4) ----
        for (int t = tid; t < OB*SQo; t += 256){
            int osub = t / SQo, e2 = t % SQo;
            int l = 0, rem = e2;
            while (rem >= (2*l+1)*(2*l+1)){ rem -= (2*l+1)*(2*l+1); ++l; }
            int w = 2*l+1;
            int i2 = rem / w, j2 = rem % w;
            int mi = i2 - l + OFFo, ni = j2 - l + OFFo;
            const float4* wp = (const float4*)(WfT + (zof(l) + rem)*P + k0);
            float re = 0.f, im = 0.f;
            #pragma unroll
            for (int h = 0; h < KB/4; ++h){
                float4 w4 = wp[h];
                float wv4[4] = {w4.x, w4.y, w4.z, w4.w};
                #pragma unroll
                for (int q = 0; q < 4; ++q){
                    float2 v = spec[(osub*KB + h*4+q)*NFo*NFo + mi*NFo + ni];
                    re += wv4[q]*v.x; im += wv4[q]*v.y;
                }
            }
            float2 acc = xacc[t];
            xacc[t] = make_float2(acc.x + re, acc.y + im);
        }
        __syncthreads();
    }

    for (int t = tid; t < OB*SQo; t += 256){
        int osub = t / SQo, e2 = t % SQo;
        Xout[((size_t)a*FO + o0 + osub)*SQo + e2] = xacc[t];
    }
}

// ---------------- fallback: fused transition kernel (round-2) ----------------
template<int T, int MODE, int OB>
__global__ __launch_bounds__(256)
void k_trans(const float2* __restrict__ Xin, const float2* __restrict__ Y,
             const float* __restrict__ Wi, const float2* __restrict__ Fi,
             const float2* __restrict__ Ff, const float* __restrict__ Wf,
             const float* __restrict__ st, const float* __restrict__ gam, const float* __restrict__ bet,
             float2* __restrict__ Xout, float2* __restrict__ bnp)
{
    constexpr int FI = cFI[T], FO = cFO[T], NL = cBO[T];
    constexpr int P = 2*NL, NF = 2*NL-1, OFF = NL-1, SQ = cSQ[T];
    constexpr int XPER = (T==0) ? 64 : SQ;
    constexpr int Tn = (T < 3) ? T + 1 : 3;
    constexpr int NLo = cBO[Tn], NFo = 2*NLo-1, OFFo = NLo-1, SQo = cSQ[Tn];
    constexpr int CH = (T==0) ? 4 : ((T==1) ? 6 : P);
    constexpr float invP2 = 1.0f/(float)(P*P);

    constexpr int szXS  = FI*XPER*8;
    constexpr int offZS = szXS;
    constexpr int szZS  = OB*SQ*8;
    constexpr int offB  = offZS + szZS;
    constexpr int offS  = offB;
    constexpr int szS   = OB*CH*NF*NF*8;
    constexpr int offT1 = offS + szS;
    constexpr int szT1  = OB*CH*P*NF*8;
    constexpr int offD  = offT1 + szT1;
    constexpr int szXV  = OB*P*P*P*4;
    constexpr int LDSZ = MODE ? (offD + szXV) : (offB + 64);

    __shared__ __align__(16) char smem[LDSZ];
    float2* xs = (float2*)(smem);
    float2* zs = (float2*)(smem + offZS);

    const int tid = threadIdx.x;
    constexpr int NOB = FO/OB;
    const int o0 = (blockIdx.x % NOB) * OB;
    const int a  = blockIdx.x / NOB;

    for (int t = tid; t < FI*XPER; t += 256) xs[t] = Xin[(size_t)a*FI*XPER + t];
    __syncthreads();

    for (int e = tid; e < OB*SQ; e += 256){
        int osub = e / SQ, rem = e % SQ;
        int o = o0 + osub;
        int l = 0;
        while (rem >= (2*l+1)*(2*l+1)){ rem -= (2*l+1)*(2*l+1); ++l; }
        int w = 2*l+1;
        int m = rem / w, n = rem % w;
        float re = 0.f, im = 0.f;
        if constexpr (T == 0){
            const float2* yb = Y + 40*l*l + o*w + n;
            for (int i = 0; i < FI; ++i){
                float2 xv2 = xs[i*64 + l*l + m];
                float2 y = yb[i*8*w];
                re += xv2.x*y.x - xv2.y*y.y;
                im += xv2.x*y.y + xv2.y*y.x;
            }
        } else {
            const float2* yb = Y + FI*FO*zof(l);
            for (int i = 0; i < FI; ++i){
                const float2* xp = &xs[i*SQ + zof(l) + m*w];
                const float2* yp = yb + ((size_t)i*w*FO + o)*w + n;
                for (int k = 0; k < w; ++k){
                    float2 xv2 = xp[k];
                    float2 y = yp[(size_t)k*FO*w];
                    re += xv2.x*y.x - xv2.y*y.y;
                    im += xv2.x*y.y + xv2.y*y.x;
                }
            }
        }
        zs[e] = make_float2(re, im);
    }
    __syncthreads();

    if constexpr (MODE == 0){
        float* wred = (float*)(smem + offB);
        if constexpr (OB == 1){
            float acc0 = 0.f, accQ = 0.f;
            for (int t = tid; t < P*NF*NF; t += 256){
                int ni = t % NF, mi = (t/NF) % NF, k = t/(NF*NF);
                int mm = mi - OFF, nn = ni - OFF;
                int am = mm < 0 ? -mm : mm, an = nn < 0 ? -nn : nn;
                int l0 = am > an ? am : an;
                float re = 0.f, im = 0.f;
                int zb = zof(l0);
                for (int l = l0; l < NL; ++l){
                    int w = 2*l+1, szl = w*w;
                    int rc = (mm + l)*w + (nn + l);
                    float wv = Wi[P*zb + k*szl + rc];
                    float2 zv = zs[zb + rc];
                    re += wv*zv.x; im += wv*zv.y;
                    zb += szl;
                }
                accQ += re*re + im*im;
                if (mm == 0 && nn == 0) acc0 += re;
            }
            for (int s = 32; s > 0; s >>= 1){ acc0 += __shfl_down(acc0, s); accQ += __shfl_down(accQ, s); }
            if ((tid & 63) == 0){ wred[tid>>6] = acc0; wred[4 + (tid>>6)] = accQ; }
            __syncthreads();
            if (tid == 0){
                float a0 = 0.f, a1 = 0.f;
                for (int u = 0; u < 4; ++u){ a0 += wred[u]; a1 += wred[4+u]; }
                bnp[(size_t)o0*NSAMP + a] = make_float2((float)(P*P)*a0, (float)(P*P)*a1);
            }
        } else {
            static_assert(OB == 1 || OB == 4, "stats path expects OB==1 or 4");
            const int wave = tid >> 6, lane = tid & 63;
            const float2* zp = zs + wave*SQ;
            float acc0 = 0.f, accQ = 0.f;
            for (int t = lane; t < P*NF*NF; t += 64){
                int ni = t % NF, mi = (t/NF) % NF, k = t/(NF*NF);
                int mm = mi - OFF, nn = ni - OFF;
                int am = mm < 0 ? -mm : mm, an = nn < 0 ? -nn : nn;
                int l0 = am > an ? am : an;
                float re = 0.f, im = 0.f;
                int zb = zof(l0);
                for (int l = l0; l < NL; ++l){
                    int w = 2*l+1, szl = w*w;
                    int rc = (mm + l)*w + (nn + l);
                    float wv = Wi[P*zb + k*szl + rc];
                    float2 zv = zp[zb + rc];
                    re += wv*zv.x; im += wv*zv.y;
                    zb += szl;
                }
                accQ += re*re + im*im;
                if (mm == 0 && nn == 0) acc0 += re;
            }
            for (int s = 32; s > 0; s >>= 1){ acc0 += __shfl_down(acc0, s); accQ += __shfl_down(accQ, s); }
            if (lane == 0) bnp[(size_t)(o0+wave)*NSAMP + a] = make_float2((float)(P*P)*acc0, (float)(P*P)*accQ);
        }
    } else {
        float2* Ssh = (float2*)(smem + offS);
        float2* t1s = (float2*)(smem + offT1);
        float*  xv  = (float*)(smem + offD);

        for (int c0 = 0; c0 < P; c0 += CH){
            for (int t = tid; t < OB*CH*NF*NF; t += 256){
                int ni = t % NF, mi = (t/NF) % NF, kk = (t/(NF*NF)) % CH, osub = t/(NF*NF*CH);
                int k = c0 + kk;
                int mm = mi - OFF, nn = ni - OFF;
                int am = mm < 0 ? -mm : mm, an = nn < 0 ? -nn : nn;
                int l0 = am > an ? am : an;
                const float2* zp = zs + osub*SQ;
                float re = 0.f, im = 0.f;
                int zb = zof(l0);
                for (int l = l0; l < NL; ++l){
                    int w = 2*l+1, szl = w*w;
                    int rc = (mm + l)*w + (nn + l);
                    float wv = Wi[P*zb + k*szl + rc];
                    float2 zv = zp[zb + rc];
                    re += wv*zv.x; im += wv*zv.y;
                    zb += szl;
                }
                Ssh[t] = make_float2(re, im);
            }
            __syncthreads();
            for (int t = tid; t < OB*CH*P*NF; t += 256){
                int ni = t % NF, al = (t/NF) % P, kk = (t/(NF*P)) % CH, osub = t/(NF*P*CH);
                const float2* sb = &Ssh[(osub*CH + kk)*NF*NF];
                float re = 0.f, im = 0.f;
                for (int mi = 0; mi < NF; ++mi){
                    float2 s = sb[mi*NF + ni];
                    float2 e = Fi[al*NF + mi];
                    re += s.x*e.x - s.y*e.y;
                    im += s.x*e.y + s.y*e.x;
                }
                t1s[t] = make_float2(re, im);
            }
            __syncthreads();
            for (int t = tid; t < OB*CH*P*P; t += 256){
                int ga = t % P, al = (t/P) % P, kk = (t/(P*P)) % CH, osub = t/(P*P*CH);
                const float2* tb = &t1s[((osub*CH + kk)*P + al)*NF];
                float re = 0.f;
                for (int ni = 0; ni < NF; ++ni){
                    float2 v = tb[ni];
                    float2 e = Fi[ga*NF + ni];
                    re += v.x*e.x - v.y*e.y;
                }
                xv[(osub*P + c0 + kk)*P*P + al*P + ga] = re;
            }
            __syncthreads();
        }

        for (int t = tid; t < OB*P*P*P; t += 256){
            int o = o0 + t/(P*P*P);
            float v = xv[t];
            xv[t] = fmaxf(0.f, (v - st[2*o])*st[2*o+1]*gam[o] + bet[o]);
        }
        __syncthreads();

        float2* t1b = (float2*)(smem);
        for (int t = tid; t < OB*P*P*NFo; t += 256){
            int n = t % NFo, kj = (t/NFo) % (P*P), osub = t/(NFo*P*P);
            const float* row = &xv[osub*P*P*P + kj*P];
            float re = 0.f, im = 0.f;
            for (int j = 0; j < P; ++j){
                float v = row[j];
                float2 e = Ff[j*NFo + n];
                re += v*e.x; im += v*e.y;
            }
            t1b[t] = make_float2(re, im);
        }
        __syncthreads();
        float2* spec = (float2*)(smem + offD);
        for (int t = tid; t < OB*P*NFo*NFo; t += 256){
            int n = t % NFo, m = (t/NFo) % NFo, k = (t/(NFo*NFo)) % P, osub = t/(NFo*NFo*P);
            const float2* tb = t1b + osub*P*P*NFo;
            float re = 0.f, im = 0.f;
            for (int j = 0; j < P; ++j){
                float2 v = tb[(k*P + j)*NFo + n];
                float2 e = Ff[j*NFo + m];
                re += v.x*e.x - v.y*e.y;
                im += v.x*e.y + v.y*e.x;
            }
            spec[t] = make_float2(re*invP2, im*invP2);
        }
        __syncthreads();
        for (int t = tid; t < OB*SQo; t += 256){
            int osub = t / SQo, e2 = t % SQo;
            int l = 0, rem = e2;
            while (rem >= (2*l+1)*(2*l+1)){ rem -= (2*l+1)*(2*l+1); ++l; }
            int w = 2*l+1;
            int i2 = rem / w, j2 = rem % w;
            int mi = i2 - l + OFFo, ni = j2 - l + OFFo;
            const float2* sp = spec + osub*P*NFo*NFo;
            float re = 0.f, im = 0.f;
            for (int k = 0; k < P; ++k){
                float wv = Wf[P*zof(l) + k*(w*w) + rem];
                float2 v = sp[(k*NFo + mi)*NFo + ni];
                re += wv*v.x; im += wv*v.y;
            }
            Xout[((size_t)a*FO + o0 + osub)*SQo + e2] = make_float2(re, im);
        }
    }
}

// ---------------- last transition (b=2) ----------------
template<int MODE>  // 0 stats, 1 integrate
__global__ __launch_bounds__(256)
void k_last(const float2* __restrict__ Xin, const float2* __restrict__ Y,
            const float* __restrict__ Wi, const float2* __restrict__ Fi,
            const float* __restrict__ st, const float* __restrict__ gam, const float* __restrict__ bet,
            const float* __restrict__ qwi, float* __restrict__ gout, float2* __restrict__ bnp)
{
    __shared__ float2 xs[320];
    __shared__ float2 zsh[640];
    const int a = blockIdx.x, tid = threadIdx.x;
    for (int t = tid; t < 320; t += 256) xs[t] = Xin[(size_t)a*320 + t];
    __syncthreads();
    for (int e = tid; e < 640; e += 256){
        int c = e / 10, rc = e % 10;
        float re = 0.f, im = 0.f;
        if (rc == 0){
            for (int i = 0; i < 32; ++i){
                float2 xv2 = xs[i*10];
                float2 y = Y[i*64 + c];
                re += xv2.x*y.x - xv2.y*y.y;
                im += xv2.x*y.y + xv2.y*y.x;
            }
        } else {
            int m = (rc-1)/3, n = (rc-1)%3;
            const float2* yb = Y + 2048;
            for (int i = 0; i < 32; ++i){
                const float2* xp = &xs[i*10 + 1 + m*3];
                for (int kk = 0; kk < 3; ++kk){
                    float2 xv2 = xp[kk];
                    float2 y = yb[((i*3+kk)*64 + c)*3 + n];
                    re += xv2.x*y.x - xv2.y*y.y;
                    im += xv2.x*y.y + xv2.y*y.x;
                }
            }
        }
        zsh[e] = make_float2(re, im);
    }
    __syncthreads();
    const int c = tid >> 2, k = tid & 3;
    float2 Sk[9];
    const float2* zc = &zsh[c*10];
    #pragma unroll
    for (int mi = 0; mi < 3; ++mi)
    #pragma unroll
    for (int ni = 0; ni < 3; ++ni){
        float wv = Wi[4 + k*9 + mi*3 + ni];
        float2 z1 = zc[1 + mi*3 + ni];
        float re = wv*z1.x, im = wv*z1.y;
        if (mi == 1 && ni == 1){
            float w0 = Wi[k];
            re += w0*zc[0].x; im += w0*zc[0].y;
        }
        Sk[mi*3+ni] = make_float2(re, im);
    }
    float mu=0.f, rs=0.f, gg=0.f, bb=0.f;
    if constexpr (MODE == 1){ mu = st[2*c]; rs = st[2*c+1]; gg = gam[c]; bb = bet[c]; }
    float accS = 0.f, accQ = 0.f, accI = 0.f;
    for (int u = 0; u < 4; ++u){
        float2 t1v[3];
        #pragma unroll
        for (int ni = 0; ni < 3; ++ni){
            float re = 0.f, im = 0.f;
            #pragma unroll
            for (int mi = 0; mi < 3; ++mi){
                float2 s = Sk[mi*3+ni];
                float2 e = Fi[u*3+mi];
                re += s.x*e.x - s.y*e.y;
                im += s.x*e.y + s.y*e.x;
            }
            t1v[ni] = make_float2(re, im);
        }
        for (int vv = 0; vv < 4; ++vv){
            float re = 0.f;
            #pragma unroll
            for (int ni = 0; ni < 3; ++ni){
                float2 e = Fi[vv*3+ni];
                re += t1v[ni].x*e.x - t1v[ni].y*e.y;
            }
            if constexpr (MODE == 0){ accS += re; accQ += re*re; }
            else accI += fmaxf(0.f, (re - mu)*rs*gg + bb);
        }
    }
    if constexpr (MODE == 0){
        accS += __shfl_down(accS,1); accQ += __shfl_down(accQ,1);
        accS += __shfl_down(accS,2); accQ += __shfl_down(accQ,2);
        if (k == 0) bnp[(size_t)c*NSAMP + a] = make_float2(accS, accQ);
    } else {
        accI *= qwi[k];
        accI += __shfl_down(accI,1);
        accI += __shfl_down(accI,2);
        if (k == 0) gout[(size_t)a*64 + c] = accI;
    }
}

// ---------------- BN stat reduction ----------------
__global__ __launch_bounds__(256)
void k_bnred(const float2* __restrict__ bnp, float* __restrict__ st, int nsamp, float minv){
    int c = blockIdx.x, tid = threadIdx.x;
    double s = 0.0, q = 0.0;
    for (int t = tid; t < nsamp; t += 256){
        float2 v = bnp[(size_t)c*nsamp + t];
        s += v.x; q += v.y;
    }
    for (int o = 32; o > 0; o >>= 1){ s += __shfl_down(s, o); q += __shfl_down(q, o); }
    __shared__ double rs_[4], rq_[4];
    if ((tid & 63) == 0){ rs_[tid>>6] = s; rq_[tid>>6] = q; }
    __syncthreads();
    if (tid == 0){
        double S = 0.0, Q = 0.0;
        for (int u = 0; u < 4; ++u){ S += rs_[u]; Q += rq_[u]; }
        double mu = S * (double)minv;
        double var = Q * (double)minv - mu*mu;
        st[2*c] = (float)mu;
        st[2*c+1] = (float)(1.0 / sqrt(var + 1e-5));
    }
}

// ---------------- MLP head ----------------
__global__ __launch_bounds__(256)
void k_fc1(const float* __restrict__ g, const float* __restrict__ W1, float* __restrict__ pre1){
    __shared__ float gs[64];
    int r = blockIdx.x, tid = threadIdx.x;
    if (tid < 64) gs[tid] = g[(size_t)r*64 + tid];
    __syncthreads();
    float acc = 0.f;
    for (int k = 0; k < 64; ++k) acc += gs[k] * W1[k*256 + tid];
    pre1[(size_t)r*256 + tid] = acc;
}

__global__ __launch_bounds__(256)
void k_colstats(const float* __restrict__ x, float* __restrict__ st, int nrow, int ncol){
    int c = blockIdx.x, tid = threadIdx.x;
    double s = 0.0, q = 0.0;
    for (int r = tid; r < nrow; r += 256){
        float v = x[(size_t)r*ncol + c];
        s += v; q += (double)v*(double)v;
    }
    for (int o = 32; o > 0; o >>= 1){ s += __shfl_down(s, o); q += __shfl_down(q, o); }
    __shared__ double rs_[4], rq_[4];
    if ((tid & 63) == 0){ rs_[tid>>6] = s; rq_[tid>>6] = q; }
    __syncthreads();
    if (tid == 0){
        double S = 0.0, Q = 0.0;
        for (int u = 0; u < 4; ++u){ S += rs_[u]; Q += rq_[u]; }
        double mu = S / nrow;
        double var = Q / nrow - mu*mu;
        st[2*c] = (float)mu;
        st[2*c+1] = (float)(1.0 / sqrt(var + 1e-5));
    }
}

__global__ __launch_bounds__(256)
void k_fc2(const float* __restrict__ pre1, const float* __restrict__ st1,
           const float* __restrict__ gw, const float* __restrict__ gb,
           const float* __restrict__ W2, float* __restrict__ pre2){
    __shared__ float hs[256];
    int r = blockIdx.x, tid = threadIdx.x;
    {
        float v = pre1[(size_t)r*256 + tid];
        v = (v - st1[2*tid]) * st1[2*tid+1] * gw[tid] + gb[tid];
        hs[tid] = fmaxf(0.f, v);
    }
    __syncthreads();
    if (tid < 64){
        float acc = 0.f;
        for (int k = 0; k < 256; ++k) acc += hs[k] * W2[k*64 + tid];
        pre2[(size_t)r*64 + tid] = acc;
    }
}

__global__ void k_masksum(const float* __restrict__ pre2, const float* __restrict__ st2,
                          const float* __restrict__ gw, const float* __restrict__ gb,
                          const int* __restrict__ atype, float* __restrict__ sm){
    int b = blockIdx.x, c = threadIdx.x;
    float mu = st2[2*c], rs = st2[2*c+1], g = gw[c], bb = gb[c];
    float acc = 0.f;
    for (int t = 0; t < 23; ++t){
        if (atype[b*23 + t] > 0){
            float v = pre2[((size_t)b*23 + t)*64 + c];
            acc += fmaxf(0.f, (v - mu)*rs*g + bb);
        }
    }
    sm[(size_t)b*64 + c] = acc;
}

__global__ __launch_bounds__(512)
void k_fc3(const float* __restrict__ sm, const float* __restrict__ W3, float* __restrict__ pre3){
    __shared__ float ss[64];
    int b = blockIdx.x, tid = threadIdx.x;
    if (tid < 64) ss[tid] = sm[(size_t)b*64 + tid];
    __syncthreads();
    float acc = 0.f;
    for (int k = 0; k < 64; ++k) acc += ss[k] * W3[k*512 + tid];
    pre3[(size_t)b*512 + tid] = acc;
}

__global__ __launch_bounds__(512)
void k_fc4(const float* __restrict__ pre3, const float* __restrict__ st3,
           const float* __restrict__ gw, const float* __restrict__ gb,
           const float* __restrict__ W4, const float* __restrict__ b4,
           float* __restrict__ out){
    int b = blockIdx.x, tid = threadIdx.x;
    float v = pre3[(size_t)b*512 + tid];
    v = fmaxf(0.f, (v - st3[2*tid]) * st3[2*tid+1] * gw[tid] + gb[tid]);
    float acc = v * W4[tid];
    for (int s = 32; s > 0; s >>= 1) acc += __shfl_down(acc, s);
    __shared__ float wr[8];
    if ((tid & 63) == 0) wr[tid>>6] = acc;
    __syncthreads();
    if (tid == 0){
        float t = 0.f;
        for (int u = 0; u < 8; ++u) t += wr[u];
        out[b] = t + b4[0];
    }
}

// ---------------------------------------------------------------------------
extern "C" void kernel_launch(void* const* d_in, const int* in_sizes, int n_in,
                              void* d_out, int out_size, void* d_ws, size_t ws_size,
                              hipStream_t stream){
    (void)in_sizes; (void)n_in; (void)out_size;
    float* ws = (float*)d_ws;
    auto F  = [&](size_t ofs){ return ws + ofs; };
    auto C2 = [&](size_t ofs){ return (float2*)(ws + ofs); };
    const bool bigws = ws_size >= WS_BIG*sizeof(float);

    const float* x    = (const float*)d_in[0];
    const int*  atype = (const int*)d_in[1];
    const float* k0 = (const float*)d_in[2];
    const float* g0 = (const float*)d_in[4];  const float* d0 = (const float*)d_in[5];
    const float* k1 = (const float*)d_in[6];
    const float* g1 = (const float*)d_in[8];  const float* d1 = (const float*)d_in[9];
    const float* k2 = (const float*)d_in[10];
    const float* g2 = (const float*)d_in[12]; const float* d2 = (const float*)d_in[13];
    const float* k3 = (const float*)d_in[14];
    const float* g3 = (const float*)d_in[16]; const float* d3 = (const float*)d_in[17];
    const float* W1 = (const float*)d_in[18];
    const float* gw1 = (const float*)d_in[20]; const float* gb1 = (const float*)d_in[21];
    const float* W2 = (const float*)d_in[22];
    const float* gw2 = (const float*)d_in[24]; const float* gb2 = (const float*)d_in[25];
    const float* W3 = (const float*)d_in[26];
    const float* gw3 = (const float*)d_in[28]; const float* gb3 = (const float*)d_in[29];
    const float* W4 = (const float*)d_in[30]; const float* b4 = (const float*)d_in[31];

    // ---- constant tables ----
    k_init_wf<<<32,256,0,stream>>>(F(OFS_WF0), 10, 8, 1);
    k_init_wf<<<32,256,0,stream>>>(F(OFS_WF1),  8, 6, 0);
    k_init_wf<<<32,256,0,stream>>>(F(OFS_WF2),  6, 4, 0);
    k_init_wf<<<32,256,0,stream>>>(F(OFS_WF3),  4, 2, 0);
    k_init_wi<<<32,256,0,stream>>>(F(OFS_WI0), 8, 8);
    k_init_wi<<<32,256,0,stream>>>(F(OFS_WI1), 6, 6);
    k_init_wi<<<32,256,0,stream>>>(F(OFS_WI2), 4, 4);
    k_init_wi<<<32,256,0,stream>>>(F(OFS_WI3), 2, 2);
    k_init_basis_s2 <<<32,256,0,stream>>>(C2(OFS_BC0), (float)(1.0/sqrt(200.0)));
    k_init_basis_so3<<<64,256,0,stream>>>(C2(OFS_BC1), 16, 6, 64, (float)(1.0/sqrt(512.0)));
    k_init_basis_so3<<<64,256,0,stream>>>(C2(OFS_BC2), 12, 4, 48, (float)(1.0/sqrt(768.0)));
    k_init_basis_so3<<<32,256,0,stream>>>(C2(OFS_BC3),  8, 2, 32, (float)(1.0/32.0));
    k_init_dft<<<2,256,0,stream>>>(C2(OFS_FF0), 20, 15, -1.0);
    k_init_dft<<<2,256,0,stream>>>(C2(OFS_FF1), 16, 11, -1.0);
    k_init_dft<<<2,256,0,stream>>>(C2(OFS_FF2), 12,  7, -1.0);
    k_init_dft<<<2,256,0,stream>>>(C2(OFS_FF3),  8,  3, -1.0);
    k_init_dft<<<2,256,0,stream>>>(C2(OFS_FI0), 16, 15,  1.0);
    k_init_dft<<<2,256,0,stream>>>(C2(OFS_FI1), 12, 11,  1.0);
    k_init_dft<<<2,256,0,stream>>>(C2(OFS_FI2),  8,  7,  1.0);
    k_init_dft<<<2,256,0,stream>>>(C2(OFS_FI3),  4,  3,  1.0);
    k_init_qwi<<<1,64,0,stream>>>(F(OFS_QWI));
    k_mkY_s2<<<dim3(3,8),256,0,stream>>>(C2(OFS_BC0), k0, C2(OFS_YC0));
    k_mkY_so3<1><<<dim3(61,6),256,0,stream>>>(C2(OFS_BC1), k1, C2(OFS_YC1));
    k_mkY_so3<2><<<dim3(98,4),256,0,stream>>>(C2(OFS_BC2), k2, C2(OFS_YC2));
    k_mkY_so3<3><<<dim3(72,2),256,0,stream>>>(C2(OFS_BC3), k3, C2(OFS_YC3));

    // ---- block 1 forward (s2 fft) -> X1 ----
    k_fwd_s2<<<NSAMP*5,256,0,stream>>>(x, C2(OFS_XA), C2(OFS_FF0), F(OFS_WF0));

    if (bigws){
        k_init_gram<<<32,256,0,stream>>>(F(OFS_WI0), F(OFS_G0), F(OFS_H0), 8);
        k_init_gram<<<32,256,0,stream>>>(F(OFS_WI1), F(OFS_G1), F(OFS_H1), 6);
        k_init_gram<<<32,256,0,stream>>>(F(OFS_WI2), F(OFS_G2), F(OFS_H2), 4);
        k_transpose_w<<<8,256,0,stream>>>(F(OFS_WI0), F(OFS_WIT0), 8, 16);
        k_transpose_w<<<4,256,0,stream>>>(F(OFS_WI1), F(OFS_WIT1), 6, 12);
        k_transpose_w<<<2,256,0,stream>>>(F(OFS_WI2), F(OFS_WIT2), 4, 8);
        k_transpose_w<<<4,256,0,stream>>>(F(OFS_WF1), F(OFS_WFT1), 6, 16);
        k_transpose_w<<<2,256,0,stream>>>(F(OFS_WF2), F(OFS_WFT2), 4, 12);
        k_transpose_w<<<1,256,0,stream>>>(F(OFS_WF3), F(OFS_WFT3), 2, 8);

        // ---- transition 0 (KB=8: halved LDS operand traffic + barriers) ----
        k_mix<0,4><<<NSAMP*2,256,0,stream>>>(C2(OFS_XA), C2(OFS_YC0), F(OFS_G0), F(OFS_H0),
                                             C2(OFS_Z), C2(OFS_BNP));
        k_bnred<<<8,256,0,stream>>>(C2(OFS_BNP), F(OFS_BNS), NSAMP, 1.0f/((float)NSAMP*4096.0f));
        k_finv<0,1,8><<<NSAMP*8,256,0,stream>>>(C2(OFS_Z), F(OFS_WIT0), C2(OFS_FI0),
                                                C2(OFS_FF1), F(OFS_WFT1), F(OFS_BNS), g0, d0, C2(OFS_XB));
        // ---- transition 1 ----
        k_mix<1,4><<<NSAMP*4,256,0,stream>>>(C2(OFS_XB), C2(OFS_YC1), F(OFS_G1), F(OFS_H1),
                                             C2(OFS_Z), C2(OFS_BNP));
        k_bnred<<<16,256,0,stream>>>(C2(OFS_BNP), F(OFS_BNS)+128, NSAMP, 1.0f/((float)NSAMP*1728.0f));
        k_finv<1,2,4><<<NSAMP*8,256,0,stream>>>(C2(OFS_Z), F(OFS_WIT1), C2(OFS_FI1),
                                                C2(OFS_FF2), F(OFS_WFT2), F(OFS_BNS)+128, g1, d1, C2(OFS_XA));
        // ---- transition 2 ----
        k_mix<2,4><<<NSAMP*8,256,0,stream>>>(C2(OFS_XA), C2(OFS_YC2), F(OFS_G2), F(OFS_H2),
                                             C2(OFS_Z), C2(OFS_BNP));
        k_bnred<<<32,256,0,stream>>>(C2(OFS_BNP), F(OFS_BNS)+256, NSAMP, 1.0f/((float)NSAMP*512.0f));
        k_finv<2,4,8><<<NSAMP*8,256,0,stream>>>(C2(OFS_Z), F(OFS_WIT2), C2(OFS_FI2),
                                                C2(OFS_FF3), F(OFS_WFT3), F(OFS_BNS)+256, g2, d2, C2(OFS_XB));
    } else {
        // ---- fallback (round-2 path) ----
        k_trans<0,0,1><<<NSAMP*8,256,0,stream>>>(C2(OFS_XA), C2(OFS_YC0), F(OFS_WI0), C2(OFS_FI0),
                                                 nullptr, nullptr, nullptr, nullptr, nullptr,
                                                 nullptr, C2(OFS_BNP));
        k_bnred<<<8,256,0,stream>>>(C2(OFS_BNP), F(OFS_BNS), NSAMP, 1.0f/((float)NSAMP*4096.0f));
        k_trans<0,1,1><<<NSAMP*8,256,0,stream>>>(C2(OFS_XA), C2(OFS_YC0), F(OFS_WI0), C2(OFS_FI0),
                                                 C2(OFS_FF1), F(OFS_WF1), F(OFS_BNS), g0, d0,
                                                 C2(OFS_XB), nullptr);
        k_trans<1,0,1><<<NSAMP*16,256,0,stream>>>(C2(OFS_XB), C2(OFS_YC1), F(OFS_WI1), C2(OFS_FI1),
                                                  nullptr, nullptr, nullptr, nullptr, nullptr,
                                                  nullptr, C2(OFS_BNP));
        k_bnred<<<16,256,0,stream>>>(C2(OFS_BNP), F(OFS_BNS)+128, NSAMP, 1.0f/((float)NSAMP*1728.0f));
        k_trans<1,1,1><<<NSAMP*16,256,0,stream>>>(C2(OFS_XB), C2(OFS_YC1), F(OFS_WI1), C2(OFS_FI1),
                                                  C2(OFS_FF2), F(OFS_WF2), F(OFS_BNS)+128, g1, d1,
                                                  C2(OFS_XA), nullptr);
        k_trans<2,0,4><<<NSAMP*8,256,0,stream>>>(C2(OFS_XA), C2(OFS_YC2), F(OFS_WI2), C2(OFS_FI2),
                                                 nullptr, nullptr, nullptr, nullptr, nullptr,
                                                 nullptr, C2(OFS_BNP));
        k_bnred<<<32,256,0,stream>>>(C2(OFS_BNP), F(OFS_BNS)+256, NSAMP, 1.0f/((float)NSAMP*512.0f));
        k_trans<2,1,4><<<NSAMP*8,256,0,stream>>>(C2(OFS_XA), C2(OFS_YC2), F(OFS_WI2), C2(OFS_FI2),
                                                 C2(OFS_FF3), F(OFS_WF3), F(OFS_BNS)+256, g2, d2,
                                                 C2(OFS_XB), nullptr);
    }

    // ---- transition 3 + integrate ----
    k_last<0><<<NSAMP,256,0,stream>>>(C2(OFS_XB), C2(OFS_YC3), F(OFS_WI3), C2(OFS_FI3),
                                      nullptr, nullptr, nullptr, nullptr, nullptr, C2(OFS_BNP));
    k_bnred<<<64,256,0,stream>>>(C2(OFS_BNP), F(OFS_BNS)+384, NSAMP, 1.0f/((float)NSAMP*64.0f));
    k_last<1><<<NSAMP,256,0,stream>>>(C2(OFS_XB), C2(OFS_YC3), F(OFS_WI3), C2(OFS_FI3),
                                      F(OFS_BNS)+384, g3, d3, F(OFS_QWI), F(OFS_GOUT), nullptr);

    // ---- MLP head ----
    k_fc1<<<NSAMP,256,0,stream>>>(F(OFS_GOUT), W1, F(OFS_PRE1));
    k_colstats<<<256,256,0,stream>>>(F(OFS_PRE1), F(OFS_ST1), NSAMP, 256);
    k_fc2<<<NSAMP,256,0,stream>>>(F(OFS_PRE1), F(OFS_ST1), gw1, gb1, W2, F(OFS_PRE2));
    k_colstats<<<64,256,0,stream>>>(F(OFS_PRE2), F(OFS_ST2), NSAMP, 64);
    k_masksum<<<64,64,0,stream>>>(F(OFS_PRE2), F(OFS_ST2), gw2, gb2, atype, F(OFS_SM));
    k_fc3<<<64,512,0,stream>>>(F(OFS_SM), W3, F(OFS_PRE3));
    k_colstats<<<512,256,0,stream>>>(F(OFS_PRE3), F(OFS_ST3), 64, 512);
    k_fc4<<<64,512,0,stream>>>(F(OFS_PRE3), F(OFS_ST3), gw3, gb3, W4, b4, (float*)d_out);
}

// Round 11
// 2509.538 us; speedup vs baseline: 1.0455x; 1.0455x over previous
//
#include <hip/hip_runtime.h>
#include <cmath>

// ---------------------------------------------------------------------------
// S2CNN regressor forward, full pipeline in fp32.
// Fast path (ws >= ~113MB): per transition
//   k_mix (mix + Gram-based BN stats, Z cached to ws) -> k_bnred ->
//   k_finv (k-register-blocked inverse + BN + ReLU + forward + accumulate,
//           AL=2 tiling in the iDFT-m phase, float4 transposed W tables).
// Round 11: settled config (= round 9). R8 (C/E/F tiling) and R10 (T0 KB=8)
// both regressed via VGPR-limited occupancy; KB=4 at T0 is the register-
// budget optimum of this decomposition.
// Fallback path (small ws): round-2 recompute design (~47MB).
// ---------------------------------------------------------------------------

#define NSAMP 1472   // 64 batch * 23 atoms
#define PI_D 3.14159265358979323846

constexpr int cBI[4] = {10, 8, 6, 4};
constexpr int cBO[4] = {8, 6, 4, 2};
constexpr int cFI[4] = {5, 8, 16, 32};
constexpr int cFO[4] = {8, 16, 32, 64};
constexpr int cG [4] = {40, 64, 48, 32};
constexpr int cSQ[4] = {680, 286, 84, 10};   // sum_{l<b_out} (2l+1)^2

__host__ __device__ constexpr int zof(int l) { return (4*l*l*l - l)/3; }
constexpr int cmax2(int a, int b){ return a > b ? a : b; }
constexpr int cmax3(int a, int b, int c){ return cmax2(cmax2(a,b), c); }

// ---------------- workspace layout (float units) ----------------
constexpr size_t al64(size_t x){ return (x + 63) & ~(size_t)63; }
constexpr size_t OFS_WF0 = 0;
constexpr size_t OFS_WF1 = al64(OFS_WF0 + 20*64);
constexpr size_t OFS_WF2 = al64(OFS_WF1 + 16*286);
constexpr size_t OFS_WF3 = al64(OFS_WF2 + 12*84);
constexpr size_t OFS_WI0 = al64(OFS_WF3 + 8*10);
constexpr size_t OFS_WI1 = al64(OFS_WI0 + 16*680);
constexpr size_t OFS_WI2 = al64(OFS_WI1 + 12*286);
constexpr size_t OFS_WI3 = al64(OFS_WI2 + 8*84);
constexpr size_t OFS_BC0 = al64(OFS_WI3 + 4*10);
constexpr size_t OFS_BC1 = al64(OFS_BC0 + 2*40*64);
constexpr size_t OFS_BC2 = al64(OFS_BC1 + 2*64*286);
constexpr size_t OFS_BC3 = al64(OFS_BC2 + 2*48*84);
constexpr size_t OFS_FF0 = al64(OFS_BC3 + 2*32*10);
constexpr size_t OFS_FF1 = al64(OFS_FF0 + 2*20*15);
constexpr size_t OFS_FF2 = al64(OFS_FF1 + 2*16*11);
constexpr size_t OFS_FF3 = al64(OFS_FF2 + 2*12*7);
constexpr size_t OFS_FI0 = al64(OFS_FF3 + 2*8*3);
constexpr size_t OFS_FI1 = al64(OFS_FI0 + 2*16*15);
constexpr size_t OFS_FI2 = al64(OFS_FI1 + 2*12*11);
constexpr size_t OFS_FI3 = al64(OFS_FI2 + 2*8*7);
constexpr size_t OFS_QWI = al64(OFS_FI3 + 2*4*3);
constexpr size_t OFS_YC0 = al64(OFS_QWI + 4);
constexpr size_t OFS_YC1 = al64(OFS_YC0 + 2*5*8*64);
constexpr size_t OFS_YC2 = al64(OFS_YC1 + 2*8*16*286);
constexpr size_t OFS_YC3 = al64(OFS_YC2 + 2*16*32*84);
constexpr size_t OFS_BNP = al64(OFS_YC3 + 2*32*64*10);
constexpr size_t OFS_BNS = al64(OFS_BNP + (size_t)2*64*NSAMP);
constexpr size_t OFS_ST1 = al64(OFS_BNS + 512);
constexpr size_t OFS_ST2 = al64(OFS_ST1 + 512);
constexpr size_t OFS_ST3 = al64(OFS_ST2 + 128);
constexpr size_t OFS_GOUT= al64(OFS_ST3 + 1024);
constexpr size_t OFS_PRE1= al64(OFS_GOUT + (size_t)NSAMP*64);
constexpr size_t OFS_PRE2= al64(OFS_PRE1 + (size_t)NSAMP*256);
constexpr size_t OFS_SM  = al64(OFS_PRE2 + (size_t)NSAMP*64);
constexpr size_t OFS_PRE3= al64(OFS_SM + 64*64);
constexpr size_t OFS_XA  = al64(OFS_PRE3 + 64*512);
constexpr size_t OFS_XB  = al64(OFS_XA + (size_t)2*NSAMP*16*84);
constexpr size_t WS_FLOATS = OFS_XB + (size_t)2*NSAMP*8*286;
constexpr size_t OFS_G0 = al64(WS_FLOATS);
constexpr size_t OFS_G1 = al64(OFS_G0 + 64*225);
constexpr size_t OFS_G2 = al64(OFS_G1 + 36*121);
constexpr size_t OFS_H0 = al64(OFS_G2 + 16*49);
constexpr size_t OFS_H1 = OFS_H0 + 8;
constexpr size_t OFS_H2 = OFS_H1 + 8;
constexpr size_t OFS_Z  = al64(OFS_H2 + 8);
constexpr size_t OFS_WIT0 = al64(OFS_Z + (size_t)2*NSAMP*8*680);
constexpr size_t OFS_WIT1 = al64(OFS_WIT0 + 680*16);
constexpr size_t OFS_WIT2 = al64(OFS_WIT1 + 286*12);
constexpr size_t OFS_WFT1 = al64(OFS_WIT2 + 84*8);
constexpr size_t OFS_WFT2 = al64(OFS_WFT1 + 286*16);
constexpr size_t OFS_WFT3 = al64(OFS_WFT2 + 84*12);
constexpr size_t WS_BIG = al64(OFS_WFT3 + 10*8);   // ~113MB

// ---------------- device math helpers (double, init only) ----------------
__device__ double dfact(int n){ double r = 1.0; for (int i = 2; i <= n; ++i) r *= (double)i; return r; }
__device__ double dipow(double x, int n){ double r = 1.0; for (int i = 0; i < n; ++i) r *= x; return r; }

__device__ double dwig(int l, int mp, int m, double beta){
    double cb = cos(0.5*beta), sb = sin(0.5*beta);
    double pref = sqrt(dfact(l+mp)*dfact(l-mp)*dfact(l+m)*dfact(l-m));
    int s0 = (m - mp > 0) ? (m - mp) : 0;
    int s1 = (l + m < l - mp) ? (l + m) : (l - mp);
    double acc = 0.0;
    for (int s = s0; s <= s1; ++s){
        double t = 1.0/(dfact(l+m-s)*dfact(s)*dfact(mp-m+s)*dfact(l-mp-s));
        t *= dipow(cb, 2*l + m - mp - 2*s) * dipow(sb, mp - m + 2*s);
        acc += ((mp - m + s) & 1) ? -t : t;
    }
    return pref*acc;
}

__device__ double dqw(int b, int j){
    double s = 0.0;
    for (int k = 0; k < b; ++k) s += sin((2*j+1)*(2*k+1)*PI_D/(4.0*b)) / (2*k+1);
    return 2.0/b * sin(PI_D*(2*j+1)/(4.0*b)) * s;
}

// ---------------- init kernels ----------------
__global__ void k_init_wf(float* dst, int b_in, int nl, int s2mode){
    int P = 2*b_in;
    int total = 0;
    for (int l = 0; l < nl; ++l){ int w = 2*l+1; total += P * (s2mode ? w : w*w); }
    for (int idx = blockIdx.x*blockDim.x + threadIdx.x; idx < total; idx += gridDim.x*blockDim.x){
        int rem = idx, l = 0;
        for (;;){ int w = 2*l+1; int blk = P*(s2mode ? w : w*w); if (rem < blk) break; rem -= blk; ++l; }
        int w = 2*l+1, szl = s2mode ? w : w*w;
        int k = rem / szl, rc = rem % szl;
        double beta = PI_D*(2*k+1)/(4.0*b_in);
        double val = s2mode ? dwig(l, rc - l, 0, beta)
                            : dwig(l, rc / w - l, rc % w - l, beta);
        dst[idx] = (float)(val * dqw(b_in, k));
    }
}

__global__ void k_init_wi(float* dst, int b_out, int nl){
    int P = 2*b_out;
    int total = 0;
    for (int l = 0; l < nl; ++l){ int w = 2*l+1; total += P*w*w; }
    for (int idx = blockIdx.x*blockDim.x + threadIdx.x; idx < total; idx += gridDim.x*blockDim.x){
        int rem = idx, l = 0;
        for (;;){ int w = 2*l+1; int blk = P*w*w; if (rem < blk) break; rem -= blk; ++l; }
        int w = 2*l+1;
        int k = rem / (w*w), rc = rem % (w*w);
        double beta = PI_D*(2*k+1)/(4.0*b_out);
        dst[idx] = (float)((2*l+1) * dwig(l, rc / w - l, rc % w - l, beta));
    }
}

// transpose [l][k][rc] -> [(zof(l)+rc)*P + k]
__global__ void k_transpose_w(const float* __restrict__ src, float* __restrict__ dst, int nl, int P){
    int total = 0;
    for (int l = 0; l < nl; ++l){ int w = 2*l+1; total += P*w*w; }
    for (int idx = blockIdx.x*blockDim.x + threadIdx.x; idx < total; idx += gridDim.x*blockDim.x){
        int rem = idx, l = 0;
        for (;;){ int w = 2*l+1; int blk = P*w*w; if (rem < blk) break; rem -= blk; ++l; }
        int w = 2*l+1, szl = w*w;
        int k = rem / szl, rc = rem % szl;
        dst[(zof(l) + rc)*P + k] = src[P*zof(l) + k*szl + rc];
    }
}

__global__ void k_init_gram(const float* __restrict__ Wi, float* __restrict__ G,
                            float* __restrict__ h, int NL){
    int P = 2*NL, NF = 2*NL-1, OFF = NL-1;
    int total = NL*NL*NF*NF;
    for (int idx = blockIdx.x*blockDim.x + threadIdx.x; idx < total; idx += gridDim.x*blockDim.x){
        int ni = idx % NF, mi = (idx/NF) % NF;
        int l2 = (idx/(NF*NF)) % NL, l = idx/(NF*NF*NL);
        int mm = mi - OFF, nn = ni - OFF;
        int am = mm<0?-mm:mm, an = nn<0?-nn:nn;
        int l0 = am > an ? am : an;
        float acc = 0.f;
        if (l >= l0 && l2 >= l0){
            int w = 2*l+1, w2 = 2*l2+1;
            const float* p1 = Wi + P*zof(l)  + (mm+l )*w  + (nn+l );
            const float* p2 = Wi + P*zof(l2) + (mm+l2)*w2 + (nn+l2);
            for (int k = 0; k < P; ++k) acc += p1[k*w*w]*p2[k*w2*w2];
        }
        G[idx] = acc;
    }
    int gi = blockIdx.x*blockDim.x + threadIdx.x;
    if (gi < NL){
        int w = 2*gi+1;
        const float* p = Wi + P*zof(gi) + gi*w + gi;
        float acc = 0.f;
        for (int k = 0; k < P; ++k) acc += p[k*w*w];
        h[gi] = acc;
    }
}

__global__ void k_init_basis_so3(float2* dst, int n_alpha, int nl, int G, float scale){
    int total = 0;
    for (int l = 0; l < nl; ++l){ int w = 2*l+1; total += G*w*w; }
    for (int idx = blockIdx.x*blockDim.x + threadIdx.x; idx < total; idx += gridDim.x*blockDim.x){
        int rem = idx, l = 0;
        for (;;){ int w = 2*l+1; int blk = G*w*w; if (rem < blk) break; rem -= blk; ++l; }
        int w = 2*l+1;
        int g = rem / (w*w), rc = rem % (w*w);
        int mu = rc / w - l, nu = rc % w - l;
        int bi = g / (n_alpha*2), rr = g % (n_alpha*2);
        int ai = rr / 2, gi = rr % 2;
        double beta  = (bi + 1) * PI_D / 16.0;
        double alpha = 2.0*PI_D*ai / n_alpha;
        double gamma = gi ? PI_D/8.0 : -PI_D/8.0;
        double d = dwig(l, mu, nu, beta);
        double ph = mu*alpha + nu*gamma;
        dst[idx] = make_float2((float)(scale*d*cos(ph)), (float)(scale*d*sin(ph)));
    }
}

__global__ void k_init_basis_s2(float2* dst, float scale){
    int total = 40*64;
    for (int idx = blockIdx.x*blockDim.x + threadIdx.x; idx < total; idx += gridDim.x*blockDim.x){
        int rem = idx, l = 0;
        for (;;){ int w = 2*l+1; int blk = 40*w; if (rem < blk) break; rem -= blk; ++l; }
        int w = 2*l+1;
        int g = rem / w, mu = rem % w - l;
        int bi = g / 20, ai = g % 20;
        double beta  = (bi + 1) * PI_D / 16.0;
        double alpha = 2.0*PI_D*ai / 20.0;
        double d = dwig(l, mu, 0, beta);
        double ph = mu*alpha;
        dst[idx] = make_float2((float)(scale*d*cos(ph)), (float)(scale*d*sin(ph)));
    }
}

__global__ void k_init_dft(float2* dst, int P, int NF, double sign){
    int off = (NF - 1) / 2;
    int total = P*NF;
    for (int idx = blockIdx.x*blockDim.x + threadIdx.x; idx < total; idx += gridDim.x*blockDim.x){
        int j = idx / NF, mi = idx % NF;
        double arg = sign * 2.0 * PI_D * (double)j * (double)(mi - off) / (double)P;
        dst[idx] = make_float2((float)cos(arg), (float)sin(arg));
    }
}

__global__ void k_init_qwi(float* dst){
    int k = threadIdx.x;
    if (k < 4) dst[k] = (float)(dqw(2, k) / 16.0);
}

// ---------------- Y = kern (x) basis ----------------
template<int T>
__global__ __launch_bounds__(256)
void k_mkY_so3(const float2* __restrict__ Bc, const float* __restrict__ kern, float2* __restrict__ YC){
    constexpr int FI = cFI[T], FO = cFO[T], G = cG[T];
    int l = blockIdx.y;
    int w = 2*l+1, szl = w*w;
    int bbase = 0, ybase = 0;
    for (int l2 = 0; l2 < l; ++l2){ int w2 = 2*l2+1; bbase += G*w2*w2; ybase += FI*FO*w2*w2; }
    int tot = FI*FO*szl;
    for (int t = blockIdx.x*256 + threadIdx.x; t < tot; t += gridDim.x*256){
        int n = t % w, o = (t/w) % FO, k = (t/(w*FO)) % w, i = t/(w*FO*w);
        float re = 0.f, im = 0.f;
        const float* kr = kern + ((size_t)i*FO + o)*G;
        for (int g = 0; g < G; ++g){
            float kv = kr[g];
            float2 b = Bc[bbase + (g*w + n)*w + k];
            re += kv*b.x; im += kv*b.y;
        }
        YC[ybase + t] = make_float2(re, im);
    }
}

__global__ __launch_bounds__(256)
void k_mkY_s2(const float2* __restrict__ Bc, const float* __restrict__ kern, float2* __restrict__ YC){
    int l = blockIdx.y;
    int w = 2*l+1;
    int bbase = 40*l*l, ybase = 40*l*l;
    int tot = 5*8*w;
    for (int t = blockIdx.x*256 + threadIdx.x; t < tot; t += gridDim.x*256){
        int n = t % w, o = (t/w) % 8, i = t/(w*8);
        float re = 0.f, im = 0.f;
        const float* kr = kern + ((size_t)i*8 + o)*40;
        for (int g = 0; g < 40; ++g){
            float kv = kr[g];
            float2 b = Bc[bbase + g*w + n];
            re += kv*b.x; im += kv*b.y;
        }
        YC[ybase + t] = make_float2(re, im);
    }
}

// ---------------- s2 forward ----------------
__global__ __launch_bounds__(256)
void k_fwd_s2(const float* __restrict__ x, float2* __restrict__ X,
              const float2* __restrict__ Ff, const float* __restrict__ Wf){
    __shared__ float xv[400];
    __shared__ float2 xf[300];
    int tid = threadIdx.x;
    const float* src = x + (size_t)blockIdx.x * 400;
    for (int t = tid; t < 400; t += 256) xv[t] = src[t];
    __syncthreads();
    for (int t = tid; t < 300; t += 256){
        int mi = t % 15, b = t / 15;
        float re = 0.f, im = 0.f;
        for (int al = 0; al < 20; ++al){
            float v = xv[b*20 + al];
            float2 e = Ff[al*15 + mi];
            re += v*e.x; im += v*e.y;
        }
        xf[t] = make_float2(re, im);
    }
    __syncthreads();
    float2* dst = X + (size_t)blockIdx.x * 64;
    int base = 0, lo = 0;
    for (int l = 0; l < 8; ++l){
        int w = 2*l+1;
        for (int t = tid; t < w; t += 256){
            int mi = t - l + 7;
            float re = 0.f, im = 0.f;
            for (int b = 0; b < 20; ++b){
                float wv = Wf[base + b*w + t];
                float2 v = xf[b*15 + mi];
                re += wv*v.x; im += wv*v.y;
            }
            dst[lo + t] = make_float2(re, im);
        }
        base += 20*w; lo += w;
    }
}

// ---------------- fast path: mix kernel (Z + Gram stats) ----------------
template<int T, int L>
__device__ inline float2 mixE(const float2* __restrict__ xs, const float2* __restrict__ Y,
                              int o, int m, int n){
    constexpr int w = 2*L+1;
    constexpr int FI = cFI[T], FO = cFO[T], SQ = cSQ[T];
    float re = 0.f, im = 0.f;
    if constexpr (T == 0){
        const float2* yb = Y + 40*L*L + o*w + n;
        #pragma unroll
        for (int i = 0; i < FI; ++i){
            float2 x = xs[i*64 + L*L + m];
            float2 y = yb[i*8*w];
            re += x.x*y.x - x.y*y.y;
            im += x.x*y.y + x.y*y.x;
        }
    } else {
        const float2* yb = Y + FI*FO*zof(L) + (size_t)o*w + n;
        for (int i = 0; i < FI; ++i){
            const float2* xp = xs + i*SQ + zof(L) + m*w;
            const float2* yp = yb + (size_t)i*w*FO*w;
            #pragma unroll
            for (int k = 0; k < w; ++k){
                float2 x = xp[k];
                float2 y = yp[(size_t)k*FO*w];
                re += x.x*y.x - x.y*y.y;
                im += x.x*y.y + x.y*y.x;
            }
        }
    }
    return make_float2(re, im);
}

template<int T, int OB>
__global__ __launch_bounds__(256)
void k_mix(const float2* __restrict__ Xin, const float2* __restrict__ Y,
           const float* __restrict__ G, const float* __restrict__ hT,
           float2* __restrict__ Z, float2* __restrict__ bnp)
{
    constexpr int FI = cFI[T], FO = cFO[T], NL = cBO[T];
    constexpr int NF = 2*NL-1, OFF = NL-1, SQ = cSQ[T], P = 2*NL;
    constexpr int XPER = (T==0) ? 64 : SQ;
    __shared__ float2 xs[FI*XPER];
    __shared__ float2 zs[OB*SQ];
    const int tid = threadIdx.x;
    constexpr int NOB = FO/OB;
    const int o0 = (blockIdx.x % NOB)*OB;
    const int a  = blockIdx.x / NOB;
    for (int t = tid; t < FI*XPER; t += 256) xs[t] = Xin[(size_t)a*FI*XPER + t];
    __syncthreads();
    float2* Zg = Z + ((size_t)a*FO + o0)*SQ;
    for (int e = tid; e < OB*SQ; e += 256){
        int osub = e / SQ, rem = e % SQ;
        int o = o0 + osub;
        int l = 0, r2 = rem;
        while (r2 >= (2*l+1)*(2*l+1)){ r2 -= (2*l+1)*(2*l+1); ++l; }
        int w = 2*l+1;
        int m = r2 / w, n = r2 % w;
        float2 val = make_float2(0.f, 0.f);
        switch(l){
            case 0: val = mixE<T,0>(xs, Y, o, m, n); break;
            case 1: if constexpr (1 < NL) val = mixE<T,1>(xs, Y, o, m, n); break;
            case 2: if constexpr (2 < NL) val = mixE<T,2>(xs, Y, o, m, n); break;
            case 3: if constexpr (3 < NL) val = mixE<T,3>(xs, Y, o, m, n); break;
            case 4: if constexpr (4 < NL) val = mixE<T,4>(xs, Y, o, m, n); break;
            case 5: if constexpr (5 < NL) val = mixE<T,5>(xs, Y, o, m, n); break;
            case 6: if constexpr (6 < NL) val = mixE<T,6>(xs, Y, o, m, n); break;
            case 7: if constexpr (7 < NL) val = mixE<T,7>(xs, Y, o, m, n); break;
        }
        zs[e] = val;
        Zg[(size_t)osub*SQ + rem] = val;
    }
    __syncthreads();
    const int wave = tid >> 6, lane = tid & 63;
    for (int osub = wave; osub < OB; osub += 4){
        const float2* zp = zs + osub*SQ;
        float pq = 0.f, p0 = 0.f;
        for (int e = lane; e < NF*NF; e += 64){
            int mi = e / NF, ni = e % NF;
            int mm = mi - OFF, nn = ni - OFF;
            int am = mm<0?-mm:mm, an = nn<0?-nn:nn;
            float zr[8], zi[8];
            #pragma unroll
            for (int l = 0; l < NL; ++l){
                bool ok = (l >= am) && (l >= an);
                int idx = ok ? (zof(l) + (mm+l)*(2*l+1) + (nn+l)) : 0;
                float2 zv = zp[idx];
                zr[l] = ok ? zv.x : 0.f;
                zi[l] = ok ? zv.y : 0.f;
            }
            #pragma unroll
            for (int l = 0; l < NL; ++l){
                #pragma unroll
                for (int l2 = 0; l2 < NL; ++l2){
                    float g = G[(l*NL + l2)*NF*NF + e];
                    pq += g*(zr[l]*zr[l2] + zi[l]*zi[l2]);
                }
            }
        }
        if (lane < NL){
            int l = lane;
            p0 = hT[l] * zp[zof(l) + l*(2*l+1) + l].x;
        }
        for (int s = 32; s > 0; s >>= 1){ p0 += __shfl_down(p0, s); pq += __shfl_down(pq, s); }
        if (lane == 0) bnp[(size_t)(o0+osub)*NSAMP + a] = make_float2((float)(P*P)*p0, (float)(P*P)*pq);
    }
}

// ---------------- fast path: k-register-blocked inverse+BN+ReLU+forward ----------------
// WiT/WfT are k-innermost transposed tables -> float4 global loads.
// Phase B uses AL=2 tiling (al, al+P/2) to halve per-FLOP LDS bytes.
template<int T, int OB, int KB>
__global__ __launch_bounds__(256)
void k_finv(const float2* __restrict__ Z, const float* __restrict__ WiT, const float2* __restrict__ Fi,
            const float2* __restrict__ Ff, const float* __restrict__ WfT,
            const float* __restrict__ st, const float* __restrict__ gam, const float* __restrict__ bet,
            float2* __restrict__ Xout)
{
    constexpr int FO = cFO[T], NL = cBO[T];
    constexpr int P = 2*NL, NF = 2*NL-1, OFF = NL-1, SQ = cSQ[T];
    constexpr int Tn = T+1;
    constexpr int NLo = cBO[Tn], NFo = 2*NLo-1, OFFo = NLo-1, SQo = cSQ[Tn];
    constexpr float invP2 = 1.0f/(float)(P*P);
    static_assert(P % KB == 0, "KB must divide P");
    static_assert(KB % 4 == 0, "KB must be multiple of 4 for float4 tables");

    constexpr int offZS = 0;                  constexpr int szZS = OB*SQ*8;
    constexpr int offFI = offZS + szZS;       constexpr int szFI = P*NF*8;
    constexpr int offFF = offFI + szFI;       constexpr int szFF = P*NFo*8;
    constexpr int offXA = offFF + szFF;       constexpr int szXA = OB*SQo*8;
    constexpr int offR1 = offXA + szXA;
    constexpr int szR1  = cmax3(OB*KB*NF*NF*8, OB*KB*P*P*4, OB*KB*NFo*NFo*8);
    constexpr int offR2 = offR1 + szR1;       constexpr int szR2 = OB*KB*P*NF*8;
    constexpr int LDSZ  = offR2 + szR2;

    __shared__ __align__(16) char smem[LDSZ];
    float2* zs    = (float2*)(smem + offZS);
    float2* Fi_sh = (float2*)(smem + offFI);
    float2* Ff_sh = (float2*)(smem + offFF);
    float2* xacc  = (float2*)(smem + offXA);
    float2* S     = (float2*)(smem + offR1);   // region1: S / vol / spec
    float*  vol   = (float*)(smem + offR1);
    float2* spec  = (float2*)(smem + offR1);
    float2* t1    = (float2*)(smem + offR2);   // region2: t1 / t1b
    float2* t1b   = (float2*)(smem + offR2);

    const int tid = threadIdx.x;
    constexpr int NOB = FO/OB;
    const int o0 = (blockIdx.x % NOB)*OB;
    const int a  = blockIdx.x / NOB;

    for (int t = tid; t < OB*SQ; t += 256) zs[t] = Z[((size_t)a*FO + o0)*SQ + t];
    for (int t = tid; t < P*NF; t += 256)  Fi_sh[t] = Fi[t];
    for (int t = tid; t < P*NFo; t += 256) Ff_sh[t] = Ff[t];
    for (int t = tid; t < OB*SQo; t += 256) xacc[t] = make_float2(0.f, 0.f);
    __syncthreads();

    for (int k0 = 0; k0 < P; k0 += KB){
        // ---- A: S[osub][kk][mi][ni] = sum_l WiT_l[mn][k] * Z_l[mn] ----
        for (int t = tid; t < OB*NF*NF; t += 256){
            int ni = t % NF, mi = (t/NF) % NF, osub = t/(NF*NF);
            int mm = mi - OFF, nn = ni - OFF;
            int am = mm < 0 ? -mm : mm, an = nn < 0 ? -nn : nn;
            int l0 = am > an ? am : an;
            const float2* zp = zs + osub*SQ;
            float reA[KB], imA[KB];
            #pragma unroll
            for (int kk = 0; kk < KB; ++kk){ reA[kk] = 0.f; imA[kk] = 0.f; }
            int zb = zof(l0);
            for (int l = l0; l < NL; ++l){
                int w = 2*l+1, szl = w*w;
                int rc = (mm + l)*w + (nn + l);
                float2 zv = zp[zb + rc];
                const float4* wp = (const float4*)(WiT + (zb + rc)*P + k0);
                #pragma unroll
                for (int h = 0; h < KB/4; ++h){
                    float4 w4 = wp[h];
                    reA[h*4+0] += w4.x*zv.x; imA[h*4+0] += w4.x*zv.y;
                    reA[h*4+1] += w4.y*zv.x; imA[h*4+1] += w4.y*zv.y;
                    reA[h*4+2] += w4.z*zv.x; imA[h*4+2] += w4.z*zv.y;
                    reA[h*4+3] += w4.w*zv.x; imA[h*4+3] += w4.w*zv.y;
                }
                zb += szl;
            }
            #pragma unroll
            for (int kk = 0; kk < KB; ++kk)
                S[(osub*KB + kk)*NF*NF + mi*NF + ni] = make_float2(reA[kk], imA[kk]);
        }
        __syncthreads();
        // ---- B: t1[g][al][ni] = sum_mi Fi[al][mi] * S[g][mi][ni]   (AL=2 tiling) ----
        {
            constexpr int PH = P/2;
            for (int t = tid; t < OB*PH*NF; t += 256){
                int ni = t % NF, alh = (t/NF) % PH, osub = t/(NF*PH);
                int al0 = alh, al1 = alh + PH;
                float re0[KB], im0[KB], re1[KB], im1[KB];
                #pragma unroll
                for (int kk = 0; kk < KB; ++kk){ re0[kk]=0.f; im0[kk]=0.f; re1[kk]=0.f; im1[kk]=0.f; }
                for (int mi = 0; mi < NF; ++mi){
                    float2 e0 = Fi_sh[al0*NF + mi];
                    float2 e1 = Fi_sh[al1*NF + mi];
                    #pragma unroll
                    for (int kk = 0; kk < KB; ++kk){
                        float2 s = S[(osub*KB + kk)*NF*NF + mi*NF + ni];
                        re0[kk] += s.x*e0.x - s.y*e0.y;
                        im0[kk] += s.x*e0.y + s.y*e0.x;
                        re1[kk] += s.x*e1.x - s.y*e1.y;
                        im1[kk] += s.x*e1.y + s.y*e1.x;
                    }
                }
                #pragma unroll
                for (int kk = 0; kk < KB; ++kk){
                    t1[(osub*KB + kk)*P*NF + al0*NF + ni] = make_float2(re0[kk], im0[kk]);
                    t1[(osub*KB + kk)*P*NF + al1*NF + ni] = make_float2(re1[kk], im1[kk]);
                }
            }
        }
        __syncthreads();
        // ---- C: vol[g][al][ga] = relu(bn(Re sum_ni t1[g][al][ni]*Fi[ga][ni])) ----
        for (int t = tid; t < OB*P*P; t += 256){
            int ga = t % P, al = (t/P) % P, osub = t/(P*P);
            float reC[KB];
            #pragma unroll
            for (int kk = 0; kk < KB; ++kk) reC[kk] = 0.f;
            for (int ni = 0; ni < NF; ++ni){
                float2 e = Fi_sh[ga*NF + ni];
                #pragma unroll
                for (int kk = 0; kk < KB; ++kk){
                    float2 v = t1[(osub*KB + kk)*P*NF + al*NF + ni];
                    reC[kk] += v.x*e.x - v.y*e.y;
                }
            }
            int o = o0 + osub;
            float mu = st[2*o], rs = st[2*o+1], gg = gam[o], bb = bet[o];
            #pragma unroll
            for (int kk = 0; kk < KB; ++kk)
                vol[((osub*KB + kk)*P + al)*P + ga] = fmaxf(0.f, (reC[kk] - mu)*rs*gg + bb);
        }
        __syncthreads();
        // ---- E: t1b[g][j1][n] = sum_j2 vol[g][j1][j2] * Ff[j2][n] ----
        for (int t = tid; t < OB*P*NFo; t += 256){
            int n = t % NFo, j1 = (t/NFo) % P, osub = t/(NFo*P);
            float reE[KB], imE[KB];
            #pragma unroll
            for (int kk = 0; kk < KB; ++kk){ reE[kk] = 0.f; imE[kk] = 0.f; }
            for (int j2 = 0; j2 < P; ++j2){
                float2 e = Ff_sh[j2*NFo + n];
                #pragma unroll
                for (int kk = 0; kk < KB; ++kk){
                    float v = vol[((osub*KB + kk)*P + j1)*P + j2];
                    reE[kk] += v*e.x; imE[kk] += v*e.y;
                }
            }
            #pragma unroll
            for (int kk = 0; kk < KB; ++kk)
                t1b[(osub*KB + kk)*P*NFo + j1*NFo + n] = make_float2(reE[kk], imE[kk]);
        }
        __syncthreads();
        // ---- F: spec[g][m][n] = invP2 * sum_j1 Ff[j1][m] * t1b[g][j1][n] ----
        for (int t = tid; t < OB*NFo*NFo; t += 256){
            int n = t % NFo, m = (t/NFo) % NFo, osub = t/(NFo*NFo);
            float reF[KB], imF[KB];
            #pragma unroll
            for (int kk = 0; kk < KB; ++kk){ reF[kk] = 0.f; imF[kk] = 0.f; }
            for (int j1 = 0; j1 < P; ++j1){
                float2 e = Ff_sh[j1*NFo + m];
                #pragma unroll
                for (int kk = 0; kk < KB; ++kk){
                    float2 v = t1b[(osub*KB + kk)*P*NFo + j1*NFo + n];
                    reF[kk] += v.x*e.x - v.y*e.y;
                    imF[kk] += v.x*e.y + v.y*e.x;
                }
            }
            #pragma unroll
            for (int kk = 0; kk < KB; ++kk)
                spec[(osub*KB + kk)*NFo*NFo + m*NFo + n] = make_float2(reF[kk]*invP2, imF[kk]*invP2);
        }
        __syncthreads();
        // ---- G: Wigner-projected accumulate (WfT float4) ----
        for (int t = tid; t < OB*SQo; t += 256){
            int osub = t / SQo, e2 = t % SQo;
            int l = 0, rem = e2;
            while (rem >= (2*l+1)*(2*l+1)){ rem -= (2*l+1)*(2*l+1); ++l; }
            int w = 2*l+1;
            int i2 = rem / w, j2 = rem % w;
            int mi = i2 - l + OFFo, ni = j2 - l + OFFo;
            const float4* wp = (const float4*)(WfT + (zof(l) + rem)*P + k0);
            float re = 0.f, im = 0.f;
            #pragma unroll
            for (int h = 0; h < KB/4; ++h){
                float4 w4 = wp[h];
                float wv4[4] = {w4.x, w4.y, w4.z, w4.w};
                #pragma unroll
                for (int q = 0; q < 4; ++q){
                    float2 v = spec[(osub*KB + h*4+q)*NFo*NFo + mi*NFo + ni];
                    re += wv4[q]*v.x; im += wv4[q]*v.y;
                }
            }
            float2 acc = xacc[t];
            xacc[t] = make_float2(acc.x + re, acc.y + im);
        }
        __syncthreads();
    }

    for (int t = tid; t < OB*SQo; t += 256){
        int osub = t / SQo, e2 = t % SQo;
        Xout[((size_t)a*FO + o0 + osub)*SQo + e2] = xacc[t];
    }
}

// ---------------- fallback: fused transition kernel (round-2) ----------------
template<int T, int MODE, int OB>
__global__ __launch_bounds__(256)
void k_trans(const float2* __restrict__ Xin, const float2* __restrict__ Y,
             const float* __restrict__ Wi, const float2* __restrict__ Fi,
             const float2* __restrict__ Ff, const float* __restrict__ Wf,
             const float* __restrict__ st, const float* __restrict__ gam, const float* __restrict__ bet,
             float2* __restrict__ Xout, float2* __restrict__ bnp)
{
    constexpr int FI = cFI[T], FO = cFO[T], NL = cBO[T];
    constexpr int P = 2*NL, NF = 2*NL-1, OFF = NL-1, SQ = cSQ[T];
    constexpr int XPER = (T==0) ? 64 : SQ;
    constexpr int Tn = (T < 3) ? T + 1 : 3;
    constexpr int NLo = cBO[Tn], NFo = 2*NLo-1, OFFo = NLo-1, SQo = cSQ[Tn];
    constexpr int CH = (T==0) ? 4 : ((T==1) ? 6 : P);
    constexpr float invP2 = 1.0f/(float)(P*P);

    constexpr int szXS  = FI*XPER*8;
    constexpr int offZS = szXS;
    constexpr int szZS  = OB*SQ*8;
    constexpr int offB  = offZS + szZS;
    constexpr int offS  = offB;
    constexpr int szS   = OB*CH*NF*NF*8;
    constexpr int offT1 = offS + szS;
    constexpr int szT1  = OB*CH*P*NF*8;
    constexpr int offD  = offT1 + szT1;
    constexpr int szXV  = OB*P*P*P*4;
    constexpr int LDSZ = MODE ? (offD + szXV) : (offB + 64);

    __shared__ __align__(16) char smem[LDSZ];
    float2* xs = (float2*)(smem);
    float2* zs = (float2*)(smem + offZS);

    const int tid = threadIdx.x;
    constexpr int NOB = FO/OB;
    const int o0 = (blockIdx.x % NOB) * OB;
    const int a  = blockIdx.x / NOB;

    for (int t = tid; t < FI*XPER; t += 256) xs[t] = Xin[(size_t)a*FI*XPER + t];
    __syncthreads();

    for (int e = tid; e < OB*SQ; e += 256){
        int osub = e / SQ, rem = e % SQ;
        int o = o0 + osub;
        int l = 0;
        while (rem >= (2*l+1)*(2*l+1)){ rem -= (2*l+1)*(2*l+1); ++l; }
        int w = 2*l+1;
        int m = rem / w, n = rem % w;
        float re = 0.f, im = 0.f;
        if constexpr (T == 0){
            const float2* yb = Y + 40*l*l + o*w + n;
            for (int i = 0; i < FI; ++i){
                float2 xv2 = xs[i*64 + l*l + m];
                float2 y = yb[i*8*w];
                re += xv2.x*y.x - xv2.y*y.y;
                im += xv2.x*y.y + xv2.y*y.x;
            }
        } else {
            const float2* yb = Y + FI*FO*zof(l);
            for (int i = 0; i < FI; ++i){
                const float2* xp = &xs[i*SQ + zof(l) + m*w];
                const float2* yp = yb + ((size_t)i*w*FO + o)*w + n;
                for (int k = 0; k < w; ++k){
                    float2 xv2 = xp[k];
                    float2 y = yp[(size_t)k*FO*w];
                    re += xv2.x*y.x - xv2.y*y.y;
                    im += xv2.x*y.y + xv2.y*y.x;
                }
            }
        }
        zs[e] = make_float2(re, im);
    }
    __syncthreads();

    if constexpr (MODE == 0){
        float* wred = (float*)(smem + offB);
        if constexpr (OB == 1){
            float acc0 = 0.f, accQ = 0.f;
            for (int t = tid; t < P*NF*NF; t += 256){
                int ni = t % NF, mi = (t/NF) % NF, k = t/(NF*NF);
                int mm = mi - OFF, nn = ni - OFF;
                int am = mm < 0 ? -mm : mm, an = nn < 0 ? -nn : nn;
                int l0 = am > an ? am : an;
                float re = 0.f, im = 0.f;
                int zb = zof(l0);
                for (int l = l0; l < NL; ++l){
                    int w = 2*l+1, szl = w*w;
                    int rc = (mm + l)*w + (nn + l);
                    float wv = Wi[P*zb + k*szl + rc];
                    float2 zv = zs[zb + rc];
                    re += wv*zv.x; im += wv*zv.y;
                    zb += szl;
                }
                accQ += re*re + im*im;
                if (mm == 0 && nn == 0) acc0 += re;
            }
            for (int s = 32; s > 0; s >>= 1){ acc0 += __shfl_down(acc0, s); accQ += __shfl_down(accQ, s); }
            if ((tid & 63) == 0){ wred[tid>>6] = acc0; wred[4 + (tid>>6)] = accQ; }
            __syncthreads();
            if (tid == 0){
                float a0 = 0.f, a1 = 0.f;
                for (int u = 0; u < 4; ++u){ a0 += wred[u]; a1 += wred[4+u]; }
                bnp[(size_t)o0*NSAMP + a] = make_float2((float)(P*P)*a0, (float)(P*P)*a1);
            }
        } else {
            static_assert(OB == 1 || OB == 4, "stats path expects OB==1 or 4");
            const int wave = tid >> 6, lane = tid & 63;
            const float2* zp = zs + wave*SQ;
            float acc0 = 0.f, accQ = 0.f;
            for (int t = lane; t < P*NF*NF; t += 64){
                int ni = t % NF, mi = (t/NF) % NF, k = t/(NF*NF);
                int mm = mi - OFF, nn = ni - OFF;
                int am = mm < 0 ? -mm : mm, an = nn < 0 ? -nn : nn;
                int l0 = am > an ? am : an;
                float re = 0.f, im = 0.f;
                int zb = zof(l0);
                for (int l = l0; l < NL; ++l){
                    int w = 2*l+1, szl = w*w;
                    int rc = (mm + l)*w + (nn + l);
                    float wv = Wi[P*zb + k*szl + rc];
                    float2 zv = zp[zb + rc];
                    re += wv*zv.x; im += wv*zv.y;
                    zb += szl;
                }
                accQ += re*re + im*im;
                if (mm == 0 && nn == 0) acc0 += re;
            }
            for (int s = 32; s > 0; s >>= 1){ acc0 += __shfl_down(acc0, s); accQ += __shfl_down(accQ, s); }
            if (lane == 0) bnp[(size_t)(o0+wave)*NSAMP + a] = make_float2((float)(P*P)*acc0, (float)(P*P)*accQ);
        }
    } else {
        float2* Ssh = (float2*)(smem + offS);
        float2* t1s = (float2*)(smem + offT1);
        float*  xv  = (float*)(smem + offD);

        for (int c0 = 0; c0 < P; c0 += CH){
            for (int t = tid; t < OB*CH*NF*NF; t += 256){
                int ni = t % NF, mi = (t/NF) % NF, kk = (t/(NF*NF)) % CH, osub = t/(NF*NF*CH);
                int k = c0 + kk;
                int mm = mi - OFF, nn = ni - OFF;
                int am = mm < 0 ? -mm : mm, an = nn < 0 ? -nn : nn;
                int l0 = am > an ? am : an;
                const float2* zp = zs + osub*SQ;
                float re = 0.f, im = 0.f;
                int zb = zof(l0);
                for (int l = l0; l < NL; ++l){
                    int w = 2*l+1, szl = w*w;
                    int rc = (mm + l)*w + (nn + l);
                    float wv = Wi[P*zb + k*szl + rc];
                    float2 zv = zp[zb + rc];
                    re += wv*zv.x; im += wv*zv.y;
                    zb += szl;
                }
                Ssh[t] = make_float2(re, im);
            }
            __syncthreads();
            for (int t = tid; t < OB*CH*P*NF; t += 256){
                int ni = t % NF, al = (t/NF) % P, kk = (t/(NF*P)) % CH, osub = t/(NF*P*CH);
                const float2* sb = &Ssh[(osub*CH + kk)*NF*NF];
                float re = 0.f, im = 0.f;
                for (int mi = 0; mi < NF; ++mi){
                    float2 s = sb[mi*NF + ni];
                    float2 e = Fi[al*NF + mi];
                    re += s.x*e.x - s.y*e.y;
                    im += s.x*e.y + s.y*e.x;
                }
                t1s[t] = make_float2(re, im);
            }
            __syncthreads();
            for (int t = tid; t < OB*CH*P*P; t += 256){
                int ga = t % P, al = (t/P) % P, kk = (t/(P*P)) % CH, osub = t/(P*P*CH);
                const float2* tb = &t1s[((osub*CH + kk)*P + al)*NF];
                float re = 0.f;
                for (int ni = 0; ni < NF; ++ni){
                    float2 v = tb[ni];
                    float2 e = Fi[ga*NF + ni];
                    re += v.x*e.x - v.y*e.y;
                }
                xv[(osub*P + c0 + kk)*P*P + al*P + ga] = re;
            }
            __syncthreads();
        }

        for (int t = tid; t < OB*P*P*P; t += 256){
            int o = o0 + t/(P*P*P);
            float v = xv[t];
            xv[t] = fmaxf(0.f, (v - st[2*o])*st[2*o+1]*gam[o] + bet[o]);
        }
        __syncthreads();

        float2* t1b = (float2*)(smem);
        for (int t = tid; t < OB*P*P*NFo; t += 256){
            int n = t % NFo, kj = (t/NFo) % (P*P), osub = t/(NFo*P*P);
            const float* row = &xv[osub*P*P*P + kj*P];
            float re = 0.f, im = 0.f;
            for (int j = 0; j < P; ++j){
                float v = row[j];
                float2 e = Ff[j*NFo + n];
                re += v*e.x; im += v*e.y;
            }
            t1b[t] = make_float2(re, im);
        }
        __syncthreads();
        float2* spec = (float2*)(smem + offD);
        for (int t = tid; t < OB*P*NFo*NFo; t += 256){
            int n = t % NFo, m = (t/NFo) % NFo, k = (t/(NFo*NFo)) % P, osub = t/(NFo*NFo*P);
            const float2* tb = t1b + osub*P*P*NFo;
            float re = 0.f, im = 0.f;
            for (int j = 0; j < P; ++j){
                float2 v = tb[(k*P + j)*NFo + n];
                float2 e = Ff[j*NFo + m];
                re += v.x*e.x - v.y*e.y;
                im += v.x*e.y + v.y*e.x;
            }
            spec[t] = make_float2(re*invP2, im*invP2);
        }
        __syncthreads();
        for (int t = tid; t < OB*SQo; t += 256){
            int osub = t / SQo, e2 = t % SQo;
            int l = 0, rem = e2;
            while (rem >= (2*l+1)*(2*l+1)){ rem -= (2*l+1)*(2*l+1); ++l; }
            int w = 2*l+1;
            int i2 = rem / w, j2 = rem % w;
            int mi = i2 - l + OFFo, ni = j2 - l + OFFo;
            const float2* sp = spec + osub*P*NFo*NFo;
            float re = 0.f, im = 0.f;
            for (int k = 0; k < P; ++k){
                float wv = Wf[P*zof(l) + k*(w*w) + rem];
                float2 v = sp[(k*NFo + mi)*NFo + ni];
                re += wv*v.x; im += wv*v.y;
            }
            Xout[((size_t)a*FO + o0 + osub)*SQo + e2] = make_float2(re, im);
        }
    }
}

// ---------------- last transition (b=2) ----------------
template<int MODE>  // 0 stats, 1 integrate
__global__ __launch_bounds__(256)
void k_last(const float2* __restrict__ Xin, const float2* __restrict__ Y,
            const float* __restrict__ Wi, const float2* __restrict__ Fi,
            const float* __restrict__ st, const float* __restrict__ gam, const float* __restrict__ bet,
            const float* __restrict__ qwi, float* __restrict__ gout, float2* __restrict__ bnp)
{
    __shared__ float2 xs[320];
    __shared__ float2 zsh[640];
    const int a = blockIdx.x, tid = threadIdx.x;
    for (int t = tid; t < 320; t += 256) xs[t] = Xin[(size_t)a*320 + t];
    __syncthreads();
    for (int e = tid; e < 640; e += 256){
        int c = e / 10, rc = e % 10;
        float re = 0.f, im = 0.f;
        if (rc == 0){
            for (int i = 0; i < 32; ++i){
                float2 xv2 = xs[i*10];
                float2 y = Y[i*64 + c];
                re += xv2.x*y.x - xv2.y*y.y;
                im += xv2.x*y.y + xv2.y*y.x;
            }
        } else {
            int m = (rc-1)/3, n = (rc-1)%3;
            const float2* yb = Y + 2048;
            for (int i = 0; i < 32; ++i){
                const float2* xp = &xs[i*10 + 1 + m*3];
                for (int kk = 0; kk < 3; ++kk){
                    float2 xv2 = xp[kk];
                    float2 y = yb[((i*3+kk)*64 + c)*3 + n];
                    re += xv2.x*y.x - xv2.y*y.y;
                    im += xv2.x*y.y + xv2.y*y.x;
                }
            }
        }
        zsh[e] = make_float2(re, im);
    }
    __syncthreads();
    const int c = tid >> 2, k = tid & 3;
    float2 Sk[9];
    const float2* zc = &zsh[c*10];
    #pragma unroll
    for (int mi = 0; mi < 3; ++mi)
    #pragma unroll
    for (int ni = 0; ni < 3; ++ni){
        float wv = Wi[4 + k*9 + mi*3 + ni];
        float2 z1 = zc[1 + mi*3 + ni];
        float re = wv*z1.x, im = wv*z1.y;
        if (mi == 1 && ni == 1){
            float w0 = Wi[k];
            re += w0*zc[0].x; im += w0*zc[0].y;
        }
        Sk[mi*3+ni] = make_float2(re, im);
    }
    float mu=0.f, rs=0.f, gg=0.f, bb=0.f;
    if constexpr (MODE == 1){ mu = st[2*c]; rs = st[2*c+1]; gg = gam[c]; bb = bet[c]; }
    float accS = 0.f, accQ = 0.f, accI = 0.f;
    for (int u = 0; u < 4; ++u){
        float2 t1v[3];
        #pragma unroll
        for (int ni = 0; ni < 3; ++ni){
            float re = 0.f, im = 0.f;
            #pragma unroll
            for (int mi = 0; mi < 3; ++mi){
                float2 s = Sk[mi*3+ni];
                float2 e = Fi[u*3+mi];
                re += s.x*e.x - s.y*e.y;
                im += s.x*e.y + s.y*e.x;
            }
            t1v[ni] = make_float2(re, im);
        }
        for (int vv = 0; vv < 4; ++vv){
            float re = 0.f;
            #pragma unroll
            for (int ni = 0; ni < 3; ++ni){
                float2 e = Fi[vv*3+ni];
                re += t1v[ni].x*e.x - t1v[ni].y*e.y;
            }
            if constexpr (MODE == 0){ accS += re; accQ += re*re; }
            else accI += fmaxf(0.f, (re - mu)*rs*gg + bb);
        }
    }
    if constexpr (MODE == 0){
        accS += __shfl_down(accS,1); accQ += __shfl_down(accQ,1);
        accS += __shfl_down(accS,2); accQ += __shfl_down(accQ,2);
        if (k == 0) bnp[(size_t)c*NSAMP + a] = make_float2(accS, accQ);
    } else {
        accI *= qwi[k];
        accI += __shfl_down(accI,1);
        accI += __shfl_down(accI,2);
        if (k == 0) gout[(size_t)a*64 + c] = accI;
    }
}

// ---------------- BN stat reduction ----------------
__global__ __launch_bounds__(256)
void k_bnred(const float2* __restrict__ bnp, float* __restrict__ st, int nsamp, float minv){
    int c = blockIdx.x, tid = threadIdx.x;
    double s = 0.0, q = 0.0;
    for (int t = tid; t < nsamp; t += 256){
        float2 v = bnp[(size_t)c*nsamp + t];
        s += v.x; q += v.y;
    }
    for (int o = 32; o > 0; o >>= 1){ s += __shfl_down(s, o); q += __shfl_down(q, o); }
    __shared__ double rs_[4], rq_[4];
    if ((tid & 63) == 0){ rs_[tid>>6] = s; rq_[tid>>6] = q; }
    __syncthreads();
    if (tid == 0){
        double S = 0.0, Q = 0.0;
        for (int u = 0; u < 4; ++u){ S += rs_[u]; Q += rq_[u]; }
        double mu = S * (double)minv;
        double var = Q * (double)minv - mu*mu;
        st[2*c] = (float)mu;
        st[2*c+1] = (float)(1.0 / sqrt(var + 1e-5));
    }
}

// ---------------- MLP head ----------------
__global__ __launch_bounds__(256)
void k_fc1(const float* __restrict__ g, const float* __restrict__ W1, float* __restrict__ pre1){
    __shared__ float gs[64];
    int r = blockIdx.x, tid = threadIdx.x;
    if (tid < 64) gs[tid] = g[(size_t)r*64 + tid];
    __syncthreads();
    float acc = 0.f;
    for (int k = 0; k < 64; ++k) acc += gs[k] * W1[k*256 + tid];
    pre1[(size_t)r*256 + tid] = acc;
}

__global__ __launch_bounds__(256)
void k_colstats(const float* __restrict__ x, float* __restrict__ st, int nrow, int ncol){
    int c = blockIdx.x, tid = threadIdx.x;
    double s = 0.0, q = 0.0;
    for (int r = tid; r < nrow; r += 256){
        float v = x[(size_t)r*ncol + c];
        s += v; q += (double)v*(double)v;
    }
    for (int o = 32; o > 0; o >>= 1){ s += __shfl_down(s, o); q += __shfl_down(q, o); }
    __shared__ double rs_[4], rq_[4];
    if ((tid & 63) == 0){ rs_[tid>>6] = s; rq_[tid>>6] = q; }
    __syncthreads();
    if (tid == 0){
        double S = 0.0, Q = 0.0;
        for (int u = 0; u < 4; ++u){ S += rs_[u]; Q += rq_[u]; }
        double mu = S / nrow;
        double var = Q / nrow - mu*mu;
        st[2*c] = (float)mu;
        st[2*c+1] = (float)(1.0 / sqrt(var + 1e-5));
    }
}

__global__ __launch_bounds__(256)
void k_fc2(const float* __restrict__ pre1, const float* __restrict__ st1,
           const float* __restrict__ gw, const float* __restrict__ gb,
           const float* __restrict__ W2, float* __restrict__ pre2){
    __shared__ float hs[256];
    int r = blockIdx.x, tid = threadIdx.x;
    {
        float v = pre1[(size_t)r*256 + tid];
        v = (v - st1[2*tid]) * st1[2*tid+1] * gw[tid] + gb[tid];
        hs[tid] = fmaxf(0.f, v);
    }
    __syncthreads();
    if (tid < 64){
        float acc = 0.f;
        for (int k = 0; k < 256; ++k) acc += hs[k] * W2[k*64 + tid];
        pre2[(size_t)r*64 + tid] = acc;
    }
}

__global__ void k_masksum(const float* __restrict__ pre2, const float* __restrict__ st2,
                          const float* __restrict__ gw, const float* __restrict__ gb,
                          const int* __restrict__ atype, float* __restrict__ sm){
    int b = blockIdx.x, c = threadIdx.x;
    float mu = st2[2*c], rs = st2[2*c+1], g = gw[c], bb = gb[c];
    float acc = 0.f;
    for (int t = 0; t < 23; ++t){
        if (atype[b*23 + t] > 0){
            float v = pre2[((size_t)b*23 + t)*64 + c];
            acc += fmaxf(0.f, (v - mu)*rs*g + bb);
        }
    }
    sm[(size_t)b*64 + c] = acc;
}

__global__ __launch_bounds__(512)
void k_fc3(const float* __restrict__ sm, const float* __restrict__ W3, float* __restrict__ pre3){
    __shared__ float ss[64];
    int b = blockIdx.x, tid = threadIdx.x;
    if (tid < 64) ss[tid] = sm[(size_t)b*64 + tid];
    __syncthreads();
    float acc = 0.f;
    for (int k = 0; k < 64; ++k) acc += ss[k] * W3[k*512 + tid];
    pre3[(size_t)b*512 + tid] = acc;
}

__global__ __launch_bounds__(512)
void k_fc4(const float* __restrict__ pre3, const float* __restrict__ st3,
           const float* __restrict__ gw, const float* __restrict__ gb,
           const float* __restrict__ W4, const float* __restrict__ b4,
           float* __restrict__ out){
    int b = blockIdx.x, tid = threadIdx.x;
    float v = pre3[(size_t)b*512 + tid];
    v = fmaxf(0.f, (v - st3[2*tid]) * st3[2*tid+1] * gw[tid] + gb[tid]);
    float acc = v * W4[tid];
    for (int s = 32; s > 0; s >>= 1) acc += __shfl_down(acc, s);
    __shared__ float wr[8];
    if ((tid & 63) == 0) wr[tid>>6] = acc;
    __syncthreads();
    if (tid == 0){
        float t = 0.f;
        for (int u = 0; u < 8; ++u) t += wr[u];
        out[b] = t + b4[0];
    }
}

// ---------------------------------------------------------------------------
extern "C" void kernel_launch(void* const* d_in, const int* in_sizes, int n_in,
                              void* d_out, int out_size, void* d_ws, size_t ws_size,
                              hipStream_t stream){
    (void)in_sizes; (void)n_in; (void)out_size;
    float* ws = (float*)d_ws;
    auto F  = [&](size_t ofs){ return ws + ofs; };
    auto C2 = [&](size_t ofs){ return (float2*)(ws + ofs); };
    const bool bigws = ws_size >= WS_BIG*sizeof(float);

    const float* x    = (const float*)d_in[0];
    const int*  atype = (const int*)d_in[1];
    const float* k0 = (const float*)d_in[2];
    const float* g0 = (const float*)d_in[4];  const float* d0 = (const float*)d_in[5];
    const float* k1 = (const float*)d_in[6];
    const float* g1 = (const float*)d_in[8];  const float* d1 = (const float*)d_in[9];
    const float* k2 = (const float*)d_in[10];
    const float* g2 = (const float*)d_in[12]; const float* d2 = (const float*)d_in[13];
    const float* k3 = (const float*)d_in[14];
    const float* g3 = (const float*)d_in[16]; const float* d3 = (const float*)d_in[17];
    const float* W1 = (const float*)d_in[18];
    const float* gw1 = (const float*)d_in[20]; const float* gb1 = (const float*)d_in[21];
    const float* W2 = (const float*)d_in[22];
    const float* gw2 = (const float*)d_in[24]; const float* gb2 = (const float*)d_in[25];
    const float* W3 = (const float*)d_in[26];
    const float* gw3 = (const float*)d_in[28]; const float* gb3 = (const float*)d_in[29];
    const float* W4 = (const float*)d_in[30]; const float* b4 = (const float*)d_in[31];

    // ---- constant tables ----
    k_init_wf<<<32,256,0,stream>>>(F(OFS_WF0), 10, 8, 1);
    k_init_wf<<<32,256,0,stream>>>(F(OFS_WF1),  8, 6, 0);
    k_init_wf<<<32,256,0,stream>>>(F(OFS_WF2),  6, 4, 0);
    k_init_wf<<<32,256,0,stream>>>(F(OFS_WF3),  4, 2, 0);
    k_init_wi<<<32,256,0,stream>>>(F(OFS_WI0), 8, 8);
    k_init_wi<<<32,256,0,stream>>>(F(OFS_WI1), 6, 6);
    k_init_wi<<<32,256,0,stream>>>(F(OFS_WI2), 4, 4);
    k_init_wi<<<32,256,0,stream>>>(F(OFS_WI3), 2, 2);
    k_init_basis_s2 <<<32,256,0,stream>>>(C2(OFS_BC0), (float)(1.0/sqrt(200.0)));
    k_init_basis_so3<<<64,256,0,stream>>>(C2(OFS_BC1), 16, 6, 64, (float)(1.0/sqrt(512.0)));
    k_init_basis_so3<<<64,256,0,stream>>>(C2(OFS_BC2), 12, 4, 48, (float)(1.0/sqrt(768.0)));
    k_init_basis_so3<<<32,256,0,stream>>>(C2(OFS_BC3),  8, 2, 32, (float)(1.0/32.0));
    k_init_dft<<<2,256,0,stream>>>(C2(OFS_FF0), 20, 15, -1.0);
    k_init_dft<<<2,256,0,stream>>>(C2(OFS_FF1), 16, 11, -1.0);
    k_init_dft<<<2,256,0,stream>>>(C2(OFS_FF2), 12,  7, -1.0);
    k_init_dft<<<2,256,0,stream>>>(C2(OFS_FF3),  8,  3, -1.0);
    k_init_dft<<<2,256,0,stream>>>(C2(OFS_FI0), 16, 15,  1.0);
    k_init_dft<<<2,256,0,stream>>>(C2(OFS_FI1), 12, 11,  1.0);
    k_init_dft<<<2,256,0,stream>>>(C2(OFS_FI2),  8,  7,  1.0);
    k_init_dft<<<2,256,0,stream>>>(C2(OFS_FI3),  4,  3,  1.0);
    k_init_qwi<<<1,64,0,stream>>>(F(OFS_QWI));
    k_mkY_s2<<<dim3(3,8),256,0,stream>>>(C2(OFS_BC0), k0, C2(OFS_YC0));
    k_mkY_so3<1><<<dim3(61,6),256,0,stream>>>(C2(OFS_BC1), k1, C2(OFS_YC1));
    k_mkY_so3<2><<<dim3(98,4),256,0,stream>>>(C2(OFS_BC2), k2, C2(OFS_YC2));
    k_mkY_so3<3><<<dim3(72,2),256,0,stream>>>(C2(OFS_BC3), k3, C2(OFS_YC3));

    // ---- block 1 forward (s2 fft) -> X1 ----
    k_fwd_s2<<<NSAMP*5,256,0,stream>>>(x, C2(OFS_XA), C2(OFS_FF0), F(OFS_WF0));

    if (bigws){
        k_init_gram<<<32,256,0,stream>>>(F(OFS_WI0), F(OFS_G0), F(OFS_H0), 8);
        k_init_gram<<<32,256,0,stream>>>(F(OFS_WI1), F(OFS_G1), F(OFS_H1), 6);
        k_init_gram<<<32,256,0,stream>>>(F(OFS_WI2), F(OFS_G2), F(OFS_H2), 4);
        k_transpose_w<<<8,256,0,stream>>>(F(OFS_WI0), F(OFS_WIT0), 8, 16);
        k_transpose_w<<<4,256,0,stream>>>(F(OFS_WI1), F(OFS_WIT1), 6, 12);
        k_transpose_w<<<2,256,0,stream>>>(F(OFS_WI2), F(OFS_WIT2), 4, 8);
        k_transpose_w<<<4,256,0,stream>>>(F(OFS_WF1), F(OFS_WFT1), 6, 16);
        k_transpose_w<<<2,256,0,stream>>>(F(OFS_WF2), F(OFS_WFT2), 4, 12);
        k_transpose_w<<<1,256,0,stream>>>(F(OFS_WF3), F(OFS_WFT3), 2, 8);

        // ---- transition 0 ----
        k_mix<0,4><<<NSAMP*2,256,0,stream>>>(C2(OFS_XA), C2(OFS_YC0), F(OFS_G0), F(OFS_H0),
                                             C2(OFS_Z), C2(OFS_BNP));
        k_bnred<<<8,256,0,stream>>>(C2(OFS_BNP), F(OFS_BNS), NSAMP, 1.0f/((float)NSAMP*4096.0f));
        k_finv<0,1,4><<<NSAMP*8,256,0,stream>>>(C2(OFS_Z), F(OFS_WIT0), C2(OFS_FI0),
                                                C2(OFS_FF1), F(OFS_WFT1), F(OFS_BNS), g0, d0, C2(OFS_XB));
        // ---- transition 1 ----
        k_mix<1,4><<<NSAMP*4,256,0,stream>>>(C2(OFS_XB), C2(OFS_YC1), F(OFS_G1), F(OFS_H1),
                                             C2(OFS_Z), C2(OFS_BNP));
        k_bnred<<<16,256,0,stream>>>(C2(OFS_BNP), F(OFS_BNS)+128, NSAMP, 1.0f/((float)NSAMP*1728.0f));
        k_finv<1,2,4><<<NSAMP*8,256,0,stream>>>(C2(OFS_Z), F(OFS_WIT1), C2(OFS_FI1),
                                                C2(OFS_FF2), F(OFS_WFT2), F(OFS_BNS)+128, g1, d1, C2(OFS_XA));
        // ---- transition 2 ----
        k_mix<2,4><<<NSAMP*8,256,0,stream>>>(C2(OFS_XA), C2(OFS_YC2), F(OFS_G2), F(OFS_H2),
                                             C2(OFS_Z), C2(OFS_BNP));
        k_bnred<<<32,256,0,stream>>>(C2(OFS_BNP), F(OFS_BNS)+256, NSAMP, 1.0f/((float)NSAMP*512.0f));
        k_finv<2,4,8><<<NSAMP*8,256,0,stream>>>(C2(OFS_Z), F(OFS_WIT2), C2(OFS_FI2),
                                                C2(OFS_FF3), F(OFS_WFT3), F(OFS_BNS)+256, g2, d2, C2(OFS_XB));
    } else {
        // ---- fallback (round-2 path) ----
        k_trans<0,0,1><<<NSAMP*8,256,0,stream>>>(C2(OFS_XA), C2(OFS_YC0), F(OFS_WI0), C2(OFS_FI0),
                                                 nullptr, nullptr, nullptr, nullptr, nullptr,
                                                 nullptr, C2(OFS_BNP));
        k_bnred<<<8,256,0,stream>>>(C2(OFS_BNP), F(OFS_BNS), NSAMP, 1.0f/((float)NSAMP*4096.0f));
        k_trans<0,1,1><<<NSAMP*8,256,0,stream>>>(C2(OFS_XA), C2(OFS_YC0), F(OFS_WI0), C2(OFS_FI0),
                                                 C2(OFS_FF1), F(OFS_WF1), F(OFS_BNS), g0, d0,
                                                 C2(OFS_XB), nullptr);
        k_trans<1,0,1><<<NSAMP*16,256,0,stream>>>(C2(OFS_XB), C2(OFS_YC1), F(OFS_WI1), C2(OFS_FI1),
                                                  nullptr, nullptr, nullptr, nullptr, nullptr,
                                                  nullptr, C2(OFS_BNP));
        k_bnred<<<16,256,0,stream>>>(C2(OFS_BNP), F(OFS_BNS)+128, NSAMP, 1.0f/((float)NSAMP*1728.0f));
        k_trans<1,1,1><<<NSAMP*16,256,0,stream>>>(C2(OFS_XB), C2(OFS_YC1), F(OFS_WI1), C2(OFS_FI1),
                                                  C2(OFS_FF2), F(OFS_WF2), F(OFS_BNS)+128, g1, d1,
                                                  C2(OFS_XA), nullptr);
        k_trans<2,0,4><<<NSAMP*8,256,0,stream>>>(C2(OFS_XA), C2(OFS_YC2), F(OFS_WI2), C2(OFS_FI2),
                                                 nullptr, nullptr, nullptr, nullptr, nullptr,
                                                 nullptr, C2(OFS_BNP));
        k_bnred<<<32,256,0,stream>>>(C2(OFS_BNP), F(OFS_BNS)+256, NSAMP, 1.0f/((float)NSAMP*512.0f));
        k_trans<2,1,4><<<NSAMP*8,256,0,stream>>>(C2(OFS_XA), C2(OFS_YC2), F(OFS_WI2), C2(OFS_FI2),
                                                 C2(OFS_FF3), F(OFS_WF3), F(OFS_BNS)+256, g2, d2,
                                                 C2(OFS_XB), nullptr);
    }

    // ---- transition 3 + integrate ----
    k_last<0><<<NSAMP,256,0,stream>>>(C2(OFS_XB), C2(OFS_YC3), F(OFS_WI3), C2(OFS_FI3),
                                      nullptr, nullptr, nullptr, nullptr, nullptr, C2(OFS_BNP));
    k_bnred<<<64,256,0,stream>>>(C2(OFS_BNP), F(OFS_BNS)+384, NSAMP, 1.0f/((float)NSAMP*64.0f));
    k_last<1><<<NSAMP,256,0,stream>>>(C2(OFS_XB), C2(OFS_YC3), F(OFS_WI3), C2(OFS_FI3),
                                      F(OFS_BNS)+384, g3, d3, F(OFS_QWI), F(OFS_GOUT), nullptr);

    // ---- MLP head ----
    k_fc1<<<NSAMP,256,0,stream>>>(F(OFS_GOUT), W1, F(OFS_PRE1));
    k_colstats<<<256,256,0,stream>>>(F(OFS_PRE1), F(OFS_ST1), NSAMP, 256);
    k_fc2<<<NSAMP,256,0,stream>>>(F(OFS_PRE1), F(OFS_ST1), gw1, gb1, W2, F(OFS_PRE2));
    k_colstats<<<64,256,0,stream>>>(F(OFS_PRE2), F(OFS_ST2), NSAMP, 64);
    k_masksum<<<64,64,0,stream>>>(F(OFS_PRE2), F(OFS_ST2), gw2, gb2, atype, F(OFS_SM));
    k_fc3<<<64,512,0,stream>>>(F(OFS_SM), W3, F(OFS_PRE3));
    k_colstats<<<512,256,0,stream>>>(F(OFS_PRE3), F(OFS_ST3), 64, 512);
    k_fc4<<<64,512,0,stream>>>(F(OFS_PRE3), F(OFS_ST3), gw3, gb3, W4, b4, (float*)d_out);
}